// Round 9
// baseline (139.316 us; speedup 1.0000x reference)
//
#include <hip/hip_runtime.h>
#include <math.h>

#define NB 11
#define PAD 5
#define DIM 128
#define NN 121        // NB*NB
#define S_TOT 484     // HEADS*NN
#define IMG 64
#define TILE 8        // pixels per block (x-contiguous)
#define PDIM 74       // IMG + 2*PAD
#define LN_EPS 1e-5f

// Prologue: zero-padded kv copy into workspace: pkv[b][py][px][c]
__global__ __launch_bounds__(128) void pad_kernel(const float* __restrict__ kv,
                                                  float* __restrict__ pkv) {
    const int row = blockIdx.x;            // 0 .. 2*74*74-1
    const int b  = row / (PDIM * PDIM);
    const int rr = row - b * PDIM * PDIM;
    const int py = rr / PDIM;
    const int px = rr - py * PDIM;
    const int ky = py - PAD, kx = px - PAD;
    float v = 0.f;
    if ((unsigned)ky < (unsigned)IMG && (unsigned)kx < (unsigned)IMG)
        v = kv[(((size_t)b * IMG + ky) * IMG + kx) * DIM + threadIdx.x];
    pkv[(size_t)row * DIM + threadIdx.x] = v;
}

// Single-arg launch bounds ONLY: (512,8)/(256,8) capped VGPR at 32 and spilled.
template<bool PADDED>
__global__ __launch_bounds__(512) void nca_kernel(
    const float* __restrict__ q, const float* __restrict__ kvsrc,
    const float* __restrict__ pos, const float* __restrict__ w,
    const float* __restrict__ bias, const float* __restrict__ gam,
    const float* __restrict__ bet, float* __restrict__ out)
{
    const int tile = blockIdx.x;         // 1024 tiles of 8 pixels along x
    const int pix0 = tile * TILE;
    const int x0 = pix0 & 63;
    const int y  = (pix0 >> 6) & 63;
    const int b  = pix0 >> 12;
    const int tid = threadIdx.x;

    __shared__ float qs[TILE][DIM];      // q, later x = q + gelu(mlp)
    __shared__ float sc[S_TOT][TILE];    // scores, s-major
    __shared__ float part[4][TILE][DIM]; // per-K-group partial sums

    // ---- stage q for 8 pixels (4 KB, coalesced) ----
    for (int i = tid; i < TILE * DIM; i += 512)
        qs[i >> 7][i & 127] = q[(size_t)pix0 * DIM + i];
    __syncthreads();

    // ---- phase A: scores. wave = pixel; 4 16-lane groups = 4 consecutive
    // cells p = 4*it + grp (contiguous 2KB kv/pos per wave). lane l16: chans
    // 8*l16..+7, r=l16>>2, s=4p+r, h=s/121 incremental. q slice REGISTER-
    // CACHED, reloaded only on h change (cuts qs ds_reads ~5x).
    {
        const int pix = tid >> 6;          // wave id = pixel
        const int grp = (tid >> 4) & 3;
        const int l16 = tid & 15;
        const int r   = l16 >> 2;
        const int dq  = 8 * (l16 & 3);
        const int ch  = 8 * l16;
        const int xpix = x0 + pix;

        int p = grp, i = 0, j = grp;
        int h = 0, rem = 4 * grp + r;

        const float* kvb = PADDED
            ? kvsrc + (size_t)b * PDIM * PDIM * DIM + ch
            : kvsrc + (size_t)b * IMG * IMG * DIM + ch;
        const float* posb = pos + ch;

        float4 q0 = *(const float4*)(&qs[pix][dq]);      // h = 0 slice
        float4 q1 = *(const float4*)(&qs[pix][dq + 4]);

        for (int it = 0; it < 31; ++it) {
            if (p <= 120) {
                float4 k0, k1;
                if (PADDED) {
                    const float* kp = kvb + (size_t)((y + i) * PDIM + (xpix + j)) * DIM;
                    k0 = *(const float4*)(kp);
                    k1 = *(const float4*)(kp + 4);
                } else {
                    const int ky = y + i - PAD, kx = xpix + j - PAD;
                    if (((unsigned)ky < (unsigned)IMG) && ((unsigned)kx < (unsigned)IMG)) {
                        const float* kp = kvb + (size_t)(ky * IMG + kx) * DIM;
                        k0 = *(const float4*)(kp);
                        k1 = *(const float4*)(kp + 4);
                    } else {
                        k0 = make_float4(0.f, 0.f, 0.f, 0.f);
                        k1 = make_float4(0.f, 0.f, 0.f, 0.f);
                    }
                }
                const float4 p0 = *(const float4*)(posb + (size_t)p * DIM);
                const float4 p1 = *(const float4*)(posb + (size_t)p * DIM + 4);
                float t = (k0.x + p0.x) * q0.x + (k0.y + p0.y) * q0.y
                        + (k0.z + p0.z) * q0.z + (k0.w + p0.w) * q0.w
                        + (k1.x + p1.x) * q1.x + (k1.y + p1.y) * q1.y
                        + (k1.z + p1.z) * q1.z + (k1.w + p1.w) * q1.w;
                t += __shfl_xor(t, 1, 64);
                t += __shfl_xor(t, 2, 64);
                if ((l16 & 3) == 0) sc[4 * p + r][pix] = t;
            }
            // incremental index updates (no divisions)
            p += 4; j += 4;
            if (j >= NB) { j -= NB; ++i; }
            rem += 16;
            if (rem >= NN) {
                rem -= NN; ++h;
                q0 = *(const float4*)(&qs[pix][h * 32 + dq]);
                q1 = *(const float4*)(&qs[pix][h * 32 + dq + 4]);
            }
        }
    }
    __syncthreads();

    // ---- phase B: MLP. wave = (K-group g, pixel-half ph); thread owns
    // 2 channels (l, l+64) x 4 pixels. ONE broadcast ds_read_b128 per iter.
    {
        const int l  = tid & 63;
        const int wv = tid >> 6;         // 0..7
        const int g  = wv >> 1;          // K-group: rows [g*121, +121)
        const int ph = wv & 1;           // pixel half: pixels ph*4..+3
        const float* wc  = w + (size_t)(g * NN) * DIM + l;
        const float* scp = &sc[g * NN][ph * 4];
        float a00 = 0.f, a01 = 0.f, a10 = 0.f, a11 = 0.f;
        float a20 = 0.f, a21 = 0.f, a30 = 0.f, a31 = 0.f;
        #pragma unroll 2
        for (int s = 0; s < NN; ++s) {
            const float4 sv = *(const float4*)(scp + s * 8);  // broadcast 16B
            const float w0 = wc[(size_t)s * DIM];             // coalesced
            const float w1 = wc[(size_t)s * DIM + 64];        // coalesced
            a00 += sv.x * w0; a01 += sv.x * w1;
            a10 += sv.y * w0; a11 += sv.y * w1;
            a20 += sv.z * w0; a21 += sv.z * w1;
            a30 += sv.w * w0; a31 += sv.w * w1;
        }
        const int pb = ph * 4;
        part[g][pb + 0][l] = a00; part[g][pb + 0][l + 64] = a01;
        part[g][pb + 1][l] = a10; part[g][pb + 1][l + 64] = a11;
        part[g][pb + 2][l] = a20; part[g][pb + 2][l + 64] = a21;
        part[g][pb + 3][l] = a30; part[g][pb + 3][l + 64] = a31;
    }
    __syncthreads();

    // ---- epilogue: reduce 4 partials, bias, exact GELU, residual ----
    for (int idx = tid; idx < TILE * DIM; idx += 512) {
        const int pix = idx >> 7, cc = idx & 127;
        float v = part[0][pix][cc] + part[1][pix][cc]
                + part[2][pix][cc] + part[3][pix][cc] + bias[cc];
        const float gl = 0.5f * v * (1.f + erff(v * 0.70710678118654752f));
        qs[pix][cc] += gl;               // x = q + gelu(mlp)
    }
    __syncthreads();

    // ---- LayerNorm: wave wid owns pixel wid ----
    {
        const int lane = tid & 63, wid = tid >> 6;
        const float v0 = qs[wid][lane], v1 = qs[wid][lane + 64];
        float sum = v0 + v1;
        #pragma unroll
        for (int off = 1; off < 64; off <<= 1) sum += __shfl_xor(sum, off, 64);
        const float mean = sum * (1.f / 128.f);
        const float d0 = v0 - mean, d1 = v1 - mean;
        float sq = d0 * d0 + d1 * d1;
        #pragma unroll
        for (int off = 1; off < 64; off <<= 1) sq += __shfl_xor(sq, off, 64);
        const float rstd = rsqrtf(sq * (1.f / 128.f) + LN_EPS);
        float* op = out + (size_t)(pix0 + wid) * DIM;
        op[lane]      = d0 * rstd * gam[lane]      + bet[lane];
        op[lane + 64] = d1 * rstd * gam[lane + 64] + bet[lane + 64];
    }
}

extern "C" void kernel_launch(void* const* d_in, const int* in_sizes, int n_in,
                              void* d_out, int out_size, void* d_ws, size_t ws_size,
                              hipStream_t stream) {
    const float* q    = (const float*)d_in[0];
    const float* kv   = (const float*)d_in[1];
    const float* pos  = (const float*)d_in[2];
    const float* w    = (const float*)d_in[3];
    const float* bias = (const float*)d_in[4];
    const float* gam  = (const float*)d_in[5];
    const float* bet  = (const float*)d_in[6];
    float* out = (float*)d_out;

    const int n_blocks = 2 * IMG * IMG / TILE;   // 1024
    const size_t pad_bytes = (size_t)2 * PDIM * PDIM * DIM * sizeof(float); // 5.6 MB

    if (ws_size >= pad_bytes) {
        float* pkv = (float*)d_ws;
        pad_kernel<<<2 * PDIM * PDIM, 128, 0, stream>>>(kv, pkv);
        nca_kernel<true><<<n_blocks, 512, 0, stream>>>(q, pkv, pos, w, bias, gam, bet, out);
    } else {
        nca_kernel<false><<<n_blocks, 512, 0, stream>>>(q, kv, pos, w, bias, gam, bet, out);
    }
}

// Round 10
// 134.089 us; speedup vs baseline: 1.0390x; 1.0390x over previous
//
#include <hip/hip_runtime.h>
#include <math.h>

#define NB 11
#define PAD 5
#define DIM 128
#define NN 121        // NB*NB
#define S_TOT 484     // HEADS*NN
#define IMG 64
#define TILE 8        // pixels per block (x-contiguous)
#define PDIM 74       // IMG + 2*PAD
#define LN_EPS 1e-5f

// Prologue: zero-padded kv copy into workspace: pkv[b][py][px][c]
__global__ __launch_bounds__(128) void pad_kernel(const float* __restrict__ kv,
                                                  float* __restrict__ pkv) {
    const int row = blockIdx.x;            // 0 .. 2*74*74-1
    const int b  = row / (PDIM * PDIM);
    const int rr = row - b * PDIM * PDIM;
    const int py = rr / PDIM;
    const int px = rr - py * PDIM;
    const int ky = py - PAD, kx = px - PAD;
    float v = 0.f;
    if ((unsigned)ky < (unsigned)IMG && (unsigned)kx < (unsigned)IMG)
        v = kv[(((size_t)b * IMG + ky) * IMG + kx) * DIM + threadIdx.x];
    pkv[(size_t)row * DIM + threadIdx.x] = v;
}

// Single-arg launch bounds ONLY: (512,8)/(256,8) capped VGPR at 32 and spilled.
__global__ __launch_bounds__(512) void nca_kernel(
    const float* __restrict__ q, const float* __restrict__ kvsrc,
    const float* __restrict__ pos, const float* __restrict__ w,
    const float* __restrict__ bias, const float* __restrict__ gam,
    const float* __restrict__ bet, float* __restrict__ out)
{
    const int tile = blockIdx.x;         // 1024 tiles of 8 pixels along x
    const int pix0 = tile * TILE;
    const int x0 = pix0 & 63;
    const int y  = (pix0 >> 6) & 63;
    const int b  = pix0 >> 12;
    const int tid = threadIdx.x;

    __shared__ float qs[TILE][DIM];      // q, later x = q + gelu(mlp)
    __shared__ float sc[S_TOT][TILE];    // scores, s-major
    __shared__ float part[4][TILE][DIM]; // per-K-group partial sums

    // ---- stage q for 8 pixels (4 KB, coalesced) ----
    for (int i = tid; i < TILE * DIM; i += 512)
        qs[i >> 7][i & 127] = q[(size_t)pix0 * DIM + i];
    __syncthreads();

    // ---- phase A: scores. wave = pixel; 4 16-lane groups = 4 consecutive
    // cells p = 4*it + grp (contiguous 2KB kv/pos per wave). lane l16: chans
    // 8*l16..+7, r=l16>>2, s=4p+r, h incremental. q slice register-cached.
    // Manual NEXT-ITER PREFETCH of kv+pos (clamped) to keep loads in flight.
    {
        const int pix = tid >> 6;          // wave id = pixel
        const int grp = (tid >> 4) & 3;
        const int l16 = tid & 15;
        const int r   = l16 >> 2;
        const int dq  = 8 * (l16 & 3);
        const int ch  = 8 * l16;
        const int xpix = x0 + pix;

        int p = grp, i = 0, j = grp;
        int rem = 4 * grp + r;
        int h = 0;

        const float* kvb  = kvsrc + (size_t)b * PDIM * PDIM * DIM + ch;
        const float* posb = pos + ch;

        float4 q0 = *(const float4*)(&qs[pix][dq]);      // h = 0 slice
        float4 q1 = *(const float4*)(&qs[pix][dq + 4]);

        // preload iteration 0 (always valid: p = grp <= 3)
        const float* kp0 = kvb + (size_t)((y + i) * PDIM + (xpix + j)) * DIM;
        float4 k0 = *(const float4*)(kp0);
        float4 k1 = *(const float4*)(kp0 + 4);
        float4 p0 = *(const float4*)(posb + (size_t)p * DIM);
        float4 p1 = *(const float4*)(posb + (size_t)p * DIM + 4);

        // 30 uniform iterations (valid for every grp), grp==0 tail after
        for (int it = 0; it < 30; ++it) {
            // ---- compute next indices & issue prefetch (clamped if OOB) ----
            int pn = p + 4, jn = j + 4, in = i;
            if (jn >= NB) { jn -= NB; ++in; }
            const bool vn = (pn <= 120);
            const int pc = vn ? pn : p;
            const int icc = vn ? in : i;
            const int jc = vn ? jn : j;
            const float* kpn = kvb + (size_t)((y + icc) * PDIM + (xpix + jc)) * DIM;
            float4 nk0 = *(const float4*)(kpn);
            float4 nk1 = *(const float4*)(kpn + 4);
            float4 np0 = *(const float4*)(posb + (size_t)pc * DIM);
            float4 np1 = *(const float4*)(posb + (size_t)pc * DIM + 4);

            // ---- compute current cell ----
            float t = (k0.x + p0.x) * q0.x + (k0.y + p0.y) * q0.y
                    + (k0.z + p0.z) * q0.z + (k0.w + p0.w) * q0.w
                    + (k1.x + p1.x) * q1.x + (k1.y + p1.y) * q1.y
                    + (k1.z + p1.z) * q1.z + (k1.w + p1.w) * q1.w;
            t += __shfl_xor(t, 1, 64);
            t += __shfl_xor(t, 2, 64);
            if ((l16 & 3) == 0) sc[4 * p + r][pix] = t;

            // ---- rotate ----
            k0 = nk0; k1 = nk1; p0 = np0; p1 = np1;
            p = pn; i = in; j = jn;
            rem += 16;
            if (rem >= NN) {
                rem -= NN; ++h;
                q0 = *(const float4*)(&qs[pix][h * 32 + dq]);
                q1 = *(const float4*)(&qs[pix][h * 32 + dq + 4]);
            }
        }
        if (grp == 0) {            // tail: p = 120 (prefetched regs valid)
            float t = (k0.x + p0.x) * q0.x + (k0.y + p0.y) * q0.y
                    + (k0.z + p0.z) * q0.z + (k0.w + p0.w) * q0.w
                    + (k1.x + p1.x) * q1.x + (k1.y + p1.y) * q1.y
                    + (k1.z + p1.z) * q1.z + (k1.w + p1.w) * q1.w;
            t += __shfl_xor(t, 1, 64);
            t += __shfl_xor(t, 2, 64);
            if ((l16 & 3) == 0) sc[480 + r][pix] = t;
        }
    }
    __syncthreads();

    // ---- phase B: MLP. wave = (K-group g, pixel-quad pq); lane li<32 owns
    // channel quad 4li, half-wave picks pixel sub-pair. One dwordx4 W row
    // read per wave-iter (upper half merged); 2-AHEAD software pipeline.
    {
        const int l    = tid & 63;
        const int wvid = tid >> 6;       // 0..7
        const int g    = wvid >> 1;      // K-group: rows [g*121, +121)
        const int pq   = wvid & 1;       // pixel quad
        const int half = l >> 5;
        const int li   = l & 31;
        const int c4   = 4 * li;         // channel quad
        const int px0  = pq * 4 + half * 2;

        const float* wc  = w + (size_t)(g * NN) * DIM + c4;
        const float* scp = &sc[g * NN][px0];

        float a00 = 0.f, a01 = 0.f, a02 = 0.f, a03 = 0.f;  // pixel px0
        float a10 = 0.f, a11 = 0.f, a12 = 0.f, a13 = 0.f;  // pixel px0+1

        float4 wA = *(const float4*)(wc);
        float2 sA = *(const float2*)(scp);
        float4 wB = *(const float4*)(wc + DIM);
        float2 sB = *(const float2*)(scp + 8);

        for (int s = 0; s < NN - 1; s += 2) {
            const int i2 = s + 2;
            const int i3 = (s + 3 < NN) ? (s + 3) : (NN - 1);
            float4 wC = *(const float4*)(wc + (size_t)i2 * DIM);
            float2 sC = *(const float2*)(scp + i2 * 8);
            float4 wD = *(const float4*)(wc + (size_t)i3 * DIM);
            float2 sD = *(const float2*)(scp + i3 * 8);

            a00 += sA.x * wA.x; a01 += sA.x * wA.y;
            a02 += sA.x * wA.z; a03 += sA.x * wA.w;
            a10 += sA.y * wA.x; a11 += sA.y * wA.y;
            a12 += sA.y * wA.z; a13 += sA.y * wA.w;

            a00 += sB.x * wB.x; a01 += sB.x * wB.y;
            a02 += sB.x * wB.z; a03 += sB.x * wB.w;
            a10 += sB.y * wB.x; a11 += sB.y * wB.y;
            a12 += sB.y * wB.z; a13 += sB.y * wB.w;

            wA = wC; sA = sC; wB = wD; sB = sD;
        }
        // tail: s = 120 sits in wA/sA
        a00 += sA.x * wA.x; a01 += sA.x * wA.y;
        a02 += sA.x * wA.z; a03 += sA.x * wA.w;
        a10 += sA.y * wA.x; a11 += sA.y * wA.y;
        a12 += sA.y * wA.z; a13 += sA.y * wA.w;

        *(float4*)&part[g][px0][c4]     = make_float4(a00, a01, a02, a03);
        *(float4*)&part[g][px0 + 1][c4] = make_float4(a10, a11, a12, a13);
    }
    __syncthreads();

    // ---- epilogue: reduce 4 partials, bias, exact GELU, residual ----
    for (int idx = tid; idx < TILE * DIM; idx += 512) {
        const int pix = idx >> 7, cc = idx & 127;
        float v = part[0][pix][cc] + part[1][pix][cc]
                + part[2][pix][cc] + part[3][pix][cc] + bias[cc];
        const float gl = 0.5f * v * (1.f + erff(v * 0.70710678118654752f));
        qs[pix][cc] += gl;               // x = q + gelu(mlp)
    }
    __syncthreads();

    // ---- LayerNorm: wave wid owns pixel wid ----
    {
        const int lane = tid & 63, wid = tid >> 6;
        const float v0 = qs[wid][lane], v1 = qs[wid][lane + 64];
        float sum = v0 + v1;
        #pragma unroll
        for (int off = 1; off < 64; off <<= 1) sum += __shfl_xor(sum, off, 64);
        const float mean = sum * (1.f / 128.f);
        const float d0 = v0 - mean, d1 = v1 - mean;
        float sq = d0 * d0 + d1 * d1;
        #pragma unroll
        for (int off = 1; off < 64; off <<= 1) sq += __shfl_xor(sq, off, 64);
        const float rstd = rsqrtf(sq * (1.f / 128.f) + LN_EPS);
        float* op = out + (size_t)(pix0 + wid) * DIM;
        op[lane]      = d0 * rstd * gam[lane]      + bet[lane];
        op[lane + 64] = d1 * rstd * gam[lane + 64] + bet[lane + 64];
    }
}

// Fallback without padded workspace (bounds-checked) — keeps correctness if
// ws_size is insufficient.
__global__ __launch_bounds__(512) void nca_kernel_nopad(
    const float* __restrict__ q, const float* __restrict__ kvsrc,
    const float* __restrict__ pos, const float* __restrict__ w,
    const float* __restrict__ bias, const float* __restrict__ gam,
    const float* __restrict__ bet, float* __restrict__ out)
{
    const int tile = blockIdx.x;
    const int pix0 = tile * TILE;
    const int x0 = pix0 & 63;
    const int y  = (pix0 >> 6) & 63;
    const int b  = pix0 >> 12;
    const int tid = threadIdx.x;

    __shared__ float qs[TILE][DIM];
    __shared__ float sc[S_TOT][TILE];
    __shared__ float part[4][TILE][DIM];

    for (int i = tid; i < TILE * DIM; i += 512)
        qs[i >> 7][i & 127] = q[(size_t)pix0 * DIM + i];
    __syncthreads();

    {
        const int pix = tid >> 6;
        const int grp = (tid >> 4) & 3;
        const int l16 = tid & 15;
        const int r   = l16 >> 2;
        const int dq  = 8 * (l16 & 3);
        const int ch  = 8 * l16;
        const int xpix = x0 + pix;
        int p = grp, i = 0, j = grp;
        int h = 0, rem = 4 * grp + r;
        const float* kvb  = kvsrc + (size_t)b * IMG * IMG * DIM + ch;
        const float* posb = pos + ch;
        float4 q0 = *(const float4*)(&qs[pix][dq]);
        float4 q1 = *(const float4*)(&qs[pix][dq + 4]);
        for (int it = 0; it < 31; ++it) {
            if (p <= 120) {
                float4 k0 = make_float4(0.f,0.f,0.f,0.f), k1 = k0;
                const int ky = y + i - PAD, kx = xpix + j - PAD;
                if (((unsigned)ky < (unsigned)IMG) && ((unsigned)kx < (unsigned)IMG)) {
                    const float* kp = kvb + (size_t)(ky * IMG + kx) * DIM;
                    k0 = *(const float4*)(kp);
                    k1 = *(const float4*)(kp + 4);
                }
                const float4 p0 = *(const float4*)(posb + (size_t)p * DIM);
                const float4 p1 = *(const float4*)(posb + (size_t)p * DIM + 4);
                float t = (k0.x + p0.x) * q0.x + (k0.y + p0.y) * q0.y
                        + (k0.z + p0.z) * q0.z + (k0.w + p0.w) * q0.w
                        + (k1.x + p1.x) * q1.x + (k1.y + p1.y) * q1.y
                        + (k1.z + p1.z) * q1.z + (k1.w + p1.w) * q1.w;
                t += __shfl_xor(t, 1, 64);
                t += __shfl_xor(t, 2, 64);
                if ((l16 & 3) == 0) sc[4 * p + r][pix] = t;
            }
            p += 4; j += 4;
            if (j >= NB) { j -= NB; ++i; }
            rem += 16;
            if (rem >= NN) {
                rem -= NN; ++h;
                q0 = *(const float4*)(&qs[pix][h * 32 + dq]);
                q1 = *(const float4*)(&qs[pix][h * 32 + dq + 4]);
            }
        }
    }
    __syncthreads();

    {
        const int l  = tid & 63;
        const int wv = tid >> 6;
        const int g  = wv >> 1;
        const int ph = wv & 1;
        const float* wc  = w + (size_t)(g * NN) * DIM + l;
        const float* scp = &sc[g * NN][ph * 4];
        float a00=0,a01=0,a10=0,a11=0,a20=0,a21=0,a30=0,a31=0;
        #pragma unroll 2
        for (int s = 0; s < NN; ++s) {
            const float4 sv = *(const float4*)(scp + s * 8);
            const float w0 = wc[(size_t)s * DIM];
            const float w1 = wc[(size_t)s * DIM + 64];
            a00 += sv.x * w0; a01 += sv.x * w1;
            a10 += sv.y * w0; a11 += sv.y * w1;
            a20 += sv.z * w0; a21 += sv.z * w1;
            a30 += sv.w * w0; a31 += sv.w * w1;
        }
        const int pb = ph * 4;
        part[g][pb+0][l] = a00; part[g][pb+0][l+64] = a01;
        part[g][pb+1][l] = a10; part[g][pb+1][l+64] = a11;
        part[g][pb+2][l] = a20; part[g][pb+2][l+64] = a21;
        part[g][pb+3][l] = a30; part[g][pb+3][l+64] = a31;
    }
    __syncthreads();

    for (int idx = tid; idx < TILE * DIM; idx += 512) {
        const int pix = idx >> 7, cc = idx & 127;
        float v = part[0][pix][cc] + part[1][pix][cc]
                + part[2][pix][cc] + part[3][pix][cc] + bias[cc];
        const float gl = 0.5f * v * (1.f + erff(v * 0.70710678118654752f));
        qs[pix][cc] += gl;
    }
    __syncthreads();

    {
        const int lane = tid & 63, wid = tid >> 6;
        const float v0 = qs[wid][lane], v1 = qs[wid][lane + 64];
        float sum = v0 + v1;
        #pragma unroll
        for (int off = 1; off < 64; off <<= 1) sum += __shfl_xor(sum, off, 64);
        const float mean = sum * (1.f / 128.f);
        const float d0 = v0 - mean, d1 = v1 - mean;
        float sq = d0 * d0 + d1 * d1;
        #pragma unroll
        for (int off = 1; off < 64; off <<= 1) sq += __shfl_xor(sq, off, 64);
        const float rstd = rsqrtf(sq * (1.f / 128.f) + LN_EPS);
        float* op = out + (size_t)(pix0 + wid) * DIM;
        op[lane]      = d0 * rstd * gam[lane]      + bet[lane];
        op[lane + 64] = d1 * rstd * gam[lane + 64] + bet[lane + 64];
    }
}

extern "C" void kernel_launch(void* const* d_in, const int* in_sizes, int n_in,
                              void* d_out, int out_size, void* d_ws, size_t ws_size,
                              hipStream_t stream) {
    const float* q    = (const float*)d_in[0];
    const float* kv   = (const float*)d_in[1];
    const float* pos  = (const float*)d_in[2];
    const float* w    = (const float*)d_in[3];
    const float* bias = (const float*)d_in[4];
    const float* gam  = (const float*)d_in[5];
    const float* bet  = (const float*)d_in[6];
    float* out = (float*)d_out;

    const int n_blocks = 2 * IMG * IMG / TILE;   // 1024
    const size_t pad_bytes = (size_t)2 * PDIM * PDIM * DIM * sizeof(float); // 5.6 MB

    if (ws_size >= pad_bytes) {
        float* pkv = (float*)d_ws;
        pad_kernel<<<2 * PDIM * PDIM, 128, 0, stream>>>(kv, pkv);
        nca_kernel<<<n_blocks, 512, 0, stream>>>(q, pkv, pos, w, bias, gam, bet, out);
    } else {
        nca_kernel_nopad<<<n_blocks, 512, 0, stream>>>(q, kv, pos, w, bias, gam, bet, out);
    }
}

// Round 11
// 115.281 us; speedup vs baseline: 1.2085x; 1.1632x over previous
//
#include <hip/hip_runtime.h>
#include <math.h>

#define NB 11
#define PAD 5
#define DIM 128
#define NN 121        // NB*NB
#define S_TOT 484     // HEADS*NN
#define IMG 64
#define TILE 8        // pixels per block (x-contiguous)
#define PDIM 74       // IMG + 2*PAD
#define SCP 520       // sc row stride (bf16 elems): 484 used + pad; 1040B row, 16B-aligned
#define LN_EPS 1e-5f

typedef __attribute__((ext_vector_type(8))) short bf16x8;
typedef __attribute__((ext_vector_type(4))) float f32x4;

static __device__ __forceinline__ unsigned short f2bf(float f) {
    unsigned u = __float_as_uint(f);
    u += 0x7FFF + ((u >> 16) & 1);          // round-to-nearest-even
    return (unsigned short)(u >> 16);
}

// Prologue 1: zero-padded kv copy into workspace: pkv[b][py][px][c]
__global__ __launch_bounds__(128) void pad_kernel(const float* __restrict__ kv,
                                                  float* __restrict__ pkv) {
    const int row = blockIdx.x;            // 0 .. 2*74*74-1
    const int b  = row / (PDIM * PDIM);
    const int rr = row - b * PDIM * PDIM;
    const int py = rr / PDIM;
    const int px = rr - py * PDIM;
    const int ky = py - PAD, kx = px - PAD;
    float v = 0.f;
    if ((unsigned)ky < (unsigned)IMG && (unsigned)kx < (unsigned)IMG)
        v = kv[(((size_t)b * IMG + ky) * IMG + kx) * DIM + threadIdx.x];
    pkv[(size_t)row * DIM + threadIdx.x] = v;
}

// Prologue 2: W (fp32, [484][128]) -> bf16 MFMA B-fragment layout:
// wfrag[((nt*16 + t)*64 + lane)*8 + j] = W[t*32 + (lane>>4)*8 + j][nt*16 + (lane&15)]
// zero for k >= 484. blockIdx.x = nt*16 + t.
__global__ __launch_bounds__(64) void wconv_kernel(const float* __restrict__ w,
                                                   unsigned short* __restrict__ wfrag) {
    const int t    = blockIdx.x & 15;
    const int lane = threadIdx.x;
    const int n    = ((blockIdx.x >> 4) << 4) + (lane & 15);
    const int kb   = t * 32 + ((lane >> 4) << 3);
    unsigned short v[8];
    #pragma unroll
    for (int j = 0; j < 8; ++j) {
        const int k = kb + j;
        v[j] = (k < S_TOT) ? f2bf(w[(size_t)k * DIM + n]) : (unsigned short)0;
    }
    *(uint4*)(wfrag + (((size_t)blockIdx.x * 64 + lane) << 3)) = *(const uint4*)v;
}

// Single-arg launch bounds ONLY: (512,8)/(256,8) capped VGPR at 32 and spilled.
__global__ __launch_bounds__(512) void nca_kernel(
    const float* __restrict__ q, const float* __restrict__ kvsrc,
    const float* __restrict__ pos, const unsigned short* __restrict__ wfrag,
    const float* __restrict__ bias, const float* __restrict__ gam,
    const float* __restrict__ bet, float* __restrict__ out)
{
    const int tile = blockIdx.x;         // 1024 tiles of 8 pixels along x
    const int pix0 = tile * TILE;
    const int x0 = pix0 & 63;
    const int y  = (pix0 >> 6) & 63;
    const int b  = pix0 >> 12;
    const int tid = threadIdx.x;

    __shared__ float qs[TILE][DIM];               // 4 KB: q, later x = q+gelu
    __shared__ unsigned short sc_bf[TILE][SCP];   // 8.1 KB: bf16 scores
    __shared__ float mlp[TILE][DIM];              // 4 KB: MFMA result

    // ---- stage q (coalesced) + zero sc K-pad region [484,520) ----
    for (int i = tid; i < TILE * DIM; i += 512)
        qs[i >> 7][i & 127] = q[(size_t)pix0 * DIM + i];
    for (int i = tid; i < TILE * (SCP - S_TOT); i += 512)
        sc_bf[i / (SCP - S_TOT)][S_TOT + i % (SCP - S_TOT)] = 0;
    __syncthreads();

    // ---- phase A (R10 structure): wave = pixel; 4 16-lane groups = 4
    // consecutive cells p = 4*it+grp. lane l16: chans 8*l16..+7, r=l16>>2,
    // s=4p+r, h incremental; q register-cached; next-iter kv/pos prefetch.
    {
        const int pix = tid >> 6;          // wave id = pixel
        const int grp = (tid >> 4) & 3;
        const int l16 = tid & 15;
        const int r   = l16 >> 2;
        const int dq  = 8 * (l16 & 3);
        const int ch  = 8 * l16;
        const int xpix = x0 + pix;

        int p = grp, i = 0, j = grp;
        int rem = 4 * grp + r;
        int h = 0;

        const float* kvb  = kvsrc + (size_t)b * PDIM * PDIM * DIM + ch;
        const float* posb = pos + ch;

        float4 q0 = *(const float4*)(&qs[pix][dq]);
        float4 q1 = *(const float4*)(&qs[pix][dq + 4]);

        const float* kp0 = kvb + (size_t)((y + i) * PDIM + (xpix + j)) * DIM;
        float4 k0 = *(const float4*)(kp0);
        float4 k1 = *(const float4*)(kp0 + 4);
        float4 p0 = *(const float4*)(posb + (size_t)p * DIM);
        float4 p1 = *(const float4*)(posb + (size_t)p * DIM + 4);

        for (int it = 0; it < 30; ++it) {
            int pn = p + 4, jn = j + 4, in = i;
            if (jn >= NB) { jn -= NB; ++in; }
            const bool vn = (pn <= 120);
            const int pc  = vn ? pn : p;
            const int icc = vn ? in : i;
            const int jc  = vn ? jn : j;
            const float* kpn = kvb + (size_t)((y + icc) * PDIM + (xpix + jc)) * DIM;
            float4 nk0 = *(const float4*)(kpn);
            float4 nk1 = *(const float4*)(kpn + 4);
            float4 np0 = *(const float4*)(posb + (size_t)pc * DIM);
            float4 np1 = *(const float4*)(posb + (size_t)pc * DIM + 4);

            float t = (k0.x + p0.x) * q0.x + (k0.y + p0.y) * q0.y
                    + (k0.z + p0.z) * q0.z + (k0.w + p0.w) * q0.w
                    + (k1.x + p1.x) * q1.x + (k1.y + p1.y) * q1.y
                    + (k1.z + p1.z) * q1.z + (k1.w + p1.w) * q1.w;
            t += __shfl_xor(t, 1, 64);
            t += __shfl_xor(t, 2, 64);
            if ((l16 & 3) == 0) sc_bf[pix][4 * p + r] = f2bf(t);

            k0 = nk0; k1 = nk1; p0 = np0; p1 = np1;
            p = pn; i = in; j = jn;
            rem += 16;
            if (rem >= NN) {
                rem -= NN; ++h;
                q0 = *(const float4*)(&qs[pix][h * 32 + dq]);
                q1 = *(const float4*)(&qs[pix][h * 32 + dq + 4]);
            }
        }
        if (grp == 0) {            // tail cell p = 120 (regs already loaded)
            float t = (k0.x + p0.x) * q0.x + (k0.y + p0.y) * q0.y
                    + (k0.z + p0.z) * q0.z + (k0.w + p0.w) * q0.w
                    + (k1.x + p1.x) * q1.x + (k1.y + p1.y) * q1.y
                    + (k1.z + p1.z) * q1.z + (k1.w + p1.w) * q1.w;
            t += __shfl_xor(t, 1, 64);
            t += __shfl_xor(t, 2, 64);
            if ((l16 & 3) == 0) sc_bf[pix][480 + r] = f2bf(t);
        }
    }
    __syncthreads();

    // ---- phase B: MFMA MLP. wave wv = N-tile (16 channels); K = 512 in
    // 16 steps of mfma_f32_16x16x32_bf16. A = scores (LDS, rows = pixels,
    // rows 8..15 duplicate rows 0..7 via m&7 — D rows independent, discarded).
    // B-frags: contiguous 1KB/wave global loads from wfrag, 4-deep pipeline.
    {
        const int wv   = tid >> 6;       // n-tile 0..7
        const int lane = tid & 63;
        const int m    = lane & 15;
        const int quad = lane >> 4;
        const unsigned short* bfr = wfrag + (((size_t)(wv * 16) * 64 + lane) << 3);
        const unsigned short* ap  = &sc_bf[m & 7][quad * 8];
        f32x4 acc = {0.f, 0.f, 0.f, 0.f};
        bf16x8 b0 = *(const bf16x8*)(bfr);
        bf16x8 b1 = *(const bf16x8*)(bfr + 512);
        bf16x8 b2 = *(const bf16x8*)(bfr + 1024);
        bf16x8 b3 = *(const bf16x8*)(bfr + 1536);
        #pragma unroll
        for (int t = 0; t < 16; ++t) {
            const bf16x8 a = *(const bf16x8*)(ap + t * 32);
            bf16x8 bn = b3;
            if (t + 4 < 16) bn = *(const bf16x8*)(bfr + (t + 4) * 512);
            acc = __builtin_amdgcn_mfma_f32_16x16x32_bf16(a, b0, acc, 0, 0, 0);
            b0 = b1; b1 = b2; b2 = b3; b3 = bn;
        }
        // D layout: col = lane&15 (channel in tile), row = quad*4+reg (pixel)
        if (quad < 2) {
            #pragma unroll
            for (int reg = 0; reg < 4; ++reg)
                mlp[quad * 4 + reg][wv * 16 + m] = acc[reg];
        }
    }
    __syncthreads();

    // ---- epilogue: bias, exact GELU, residual ----
    for (int idx = tid; idx < TILE * DIM; idx += 512) {
        const int pix = idx >> 7, cc = idx & 127;
        const float v = mlp[pix][cc] + bias[cc];
        const float gl = 0.5f * v * (1.f + erff(v * 0.70710678118654752f));
        qs[pix][cc] += gl;               // x = q + gelu(mlp)
    }
    __syncthreads();

    // ---- LayerNorm: wave wid owns pixel wid ----
    {
        const int lane = tid & 63, wid = tid >> 6;
        const float v0 = qs[wid][lane], v1 = qs[wid][lane + 64];
        float sum = v0 + v1;
        #pragma unroll
        for (int off = 1; off < 64; off <<= 1) sum += __shfl_xor(sum, off, 64);
        const float mean = sum * (1.f / 128.f);
        const float d0 = v0 - mean, d1 = v1 - mean;
        float sq = d0 * d0 + d1 * d1;
        #pragma unroll
        for (int off = 1; off < 64; off <<= 1) sq += __shfl_xor(sq, off, 64);
        const float rstd = rsqrtf(sq * (1.f / 128.f) + LN_EPS);
        float* op = out + (size_t)(pix0 + wid) * DIM;
        op[lane]      = d0 * rstd * gam[lane]      + bet[lane];
        op[lane + 64] = d1 * rstd * gam[lane + 64] + bet[lane + 64];
    }
}

// Fallback (fp32, bounds-checked, no workspace) — R10 nopad kernel verbatim.
__global__ __launch_bounds__(512) void nca_kernel_nopad(
    const float* __restrict__ q, const float* __restrict__ kvsrc,
    const float* __restrict__ pos, const float* __restrict__ w,
    const float* __restrict__ bias, const float* __restrict__ gam,
    const float* __restrict__ bet, float* __restrict__ out)
{
    const int tile = blockIdx.x;
    const int pix0 = tile * TILE;
    const int x0 = pix0 & 63;
    const int y  = (pix0 >> 6) & 63;
    const int b  = pix0 >> 12;
    const int tid = threadIdx.x;

    __shared__ float qs[TILE][DIM];
    __shared__ float sc[S_TOT][TILE];
    __shared__ float part[4][TILE][DIM];

    for (int i = tid; i < TILE * DIM; i += 512)
        qs[i >> 7][i & 127] = q[(size_t)pix0 * DIM + i];
    __syncthreads();

    {
        const int pix = tid >> 6;
        const int grp = (tid >> 4) & 3;
        const int l16 = tid & 15;
        const int r   = l16 >> 2;
        const int dq  = 8 * (l16 & 3);
        const int ch  = 8 * l16;
        const int xpix = x0 + pix;
        int p = grp, i = 0, j = grp;
        int h = 0, rem = 4 * grp + r;
        const float* kvb  = kvsrc + (size_t)b * IMG * IMG * DIM + ch;
        const float* posb = pos + ch;
        float4 q0 = *(const float4*)(&qs[pix][dq]);
        float4 q1 = *(const float4*)(&qs[pix][dq + 4]);
        for (int it = 0; it < 31; ++it) {
            if (p <= 120) {
                float4 k0 = make_float4(0.f,0.f,0.f,0.f), k1 = k0;
                const int ky = y + i - PAD, kx = xpix + j - PAD;
                if (((unsigned)ky < (unsigned)IMG) && ((unsigned)kx < (unsigned)IMG)) {
                    const float* kp = kvb + (size_t)(ky * IMG + kx) * DIM;
                    k0 = *(const float4*)(kp);
                    k1 = *(const float4*)(kp + 4);
                }
                const float4 p0 = *(const float4*)(posb + (size_t)p * DIM);
                const float4 p1 = *(const float4*)(posb + (size_t)p * DIM + 4);
                float t = (k0.x + p0.x) * q0.x + (k0.y + p0.y) * q0.y
                        + (k0.z + p0.z) * q0.z + (k0.w + p0.w) * q0.w
                        + (k1.x + p1.x) * q1.x + (k1.y + p1.y) * q1.y
                        + (k1.z + p1.z) * q1.z + (k1.w + p1.w) * q1.w;
                t += __shfl_xor(t, 1, 64);
                t += __shfl_xor(t, 2, 64);
                if ((l16 & 3) == 0) sc[4 * p + r][pix] = t;
            }
            p += 4; j += 4;
            if (j >= NB) { j -= NB; ++i; }
            rem += 16;
            if (rem >= NN) {
                rem -= NN; ++h;
                q0 = *(const float4*)(&qs[pix][h * 32 + dq]);
                q1 = *(const float4*)(&qs[pix][h * 32 + dq + 4]);
            }
        }
    }
    __syncthreads();

    {
        const int l  = tid & 63;
        const int wv = tid >> 6;
        const int g  = wv >> 1;
        const int ph = wv & 1;
        const float* wc  = w + (size_t)(g * NN) * DIM + l;
        const float* scp = &sc[g * NN][ph * 4];
        float a00=0,a01=0,a10=0,a11=0,a20=0,a21=0,a30=0,a31=0;
        #pragma unroll 2
        for (int s = 0; s < NN; ++s) {
            const float4 sv = *(const float4*)(scp + s * 8);
            const float w0 = wc[(size_t)s * DIM];
            const float w1 = wc[(size_t)s * DIM + 64];
            a00 += sv.x * w0; a01 += sv.x * w1;
            a10 += sv.y * w0; a11 += sv.y * w1;
            a20 += sv.z * w0; a21 += sv.z * w1;
            a30 += sv.w * w0; a31 += sv.w * w1;
        }
        const int pb = ph * 4;
        part[g][pb+0][l] = a00; part[g][pb+0][l+64] = a01;
        part[g][pb+1][l] = a10; part[g][pb+1][l+64] = a11;
        part[g][pb+2][l] = a20; part[g][pb+2][l+64] = a21;
        part[g][pb+3][l] = a30; part[g][pb+3][l+64] = a31;
    }
    __syncthreads();

    for (int idx = tid; idx < TILE * DIM; idx += 512) {
        const int pix = idx >> 7, cc = idx & 127;
        float v = part[0][pix][cc] + part[1][pix][cc]
                + part[2][pix][cc] + part[3][pix][cc] + bias[cc];
        const float gl = 0.5f * v * (1.f + erff(v * 0.70710678118654752f));
        qs[pix][cc] += gl;
    }
    __syncthreads();

    {
        const int lane = tid & 63, wid = tid >> 6;
        const float v0 = qs[wid][lane], v1 = qs[wid][lane + 64];
        float sum = v0 + v1;
        #pragma unroll
        for (int off = 1; off < 64; off <<= 1) sum += __shfl_xor(sum, off, 64);
        const float mean = sum * (1.f / 128.f);
        const float d0 = v0 - mean, d1 = v1 - mean;
        float sq = d0 * d0 + d1 * d1;
        #pragma unroll
        for (int off = 1; off < 64; off <<= 1) sq += __shfl_xor(sq, off, 64);
        const float rstd = rsqrtf(sq * (1.f / 128.f) + LN_EPS);
        float* op = out + (size_t)(pix0 + wid) * DIM;
        op[lane]      = d0 * rstd * gam[lane]      + bet[lane];
        op[lane + 64] = d1 * rstd * gam[lane + 64] + bet[lane + 64];
    }
}

extern "C" void kernel_launch(void* const* d_in, const int* in_sizes, int n_in,
                              void* d_out, int out_size, void* d_ws, size_t ws_size,
                              hipStream_t stream) {
    const float* q    = (const float*)d_in[0];
    const float* kv   = (const float*)d_in[1];
    const float* pos  = (const float*)d_in[2];
    const float* w    = (const float*)d_in[3];
    const float* bias = (const float*)d_in[4];
    const float* gam  = (const float*)d_in[5];
    const float* bet  = (const float*)d_in[6];
    float* out = (float*)d_out;

    const int n_blocks = 2 * IMG * IMG / TILE;   // 1024
    const size_t pad_bytes   = (size_t)2 * PDIM * PDIM * DIM * sizeof(float); // 5,607,424
    const size_t wfrag_bytes = (size_t)8 * 16 * 64 * 8 * sizeof(unsigned short); // 131,072

    if (ws_size >= pad_bytes + wfrag_bytes) {
        float* pkv = (float*)d_ws;
        unsigned short* wfrag = (unsigned short*)((char*)d_ws + pad_bytes);
        pad_kernel<<<2 * PDIM * PDIM, 128, 0, stream>>>(kv, pkv);
        wconv_kernel<<<128, 64, 0, stream>>>(w, wfrag);
        nca_kernel<<<n_blocks, 512, 0, stream>>>(q, pkv, pos, wfrag, bias, gam, bet, out);
    } else {
        nca_kernel_nopad<<<n_blocks, 512, 0, stream>>>(q, kv, pos, w, bias, gam, bet, out);
    }
}

// Round 12
// 113.257 us; speedup vs baseline: 1.2301x; 1.0179x over previous
//
#include <hip/hip_runtime.h>
#include <math.h>

#define NB 11
#define PAD 5
#define DIM 128
#define NN 121        // NB*NB
#define S_TOT 484     // HEADS*NN
#define IMG 64
#define TILE 8        // pixels per block (x-contiguous)
#define PDIM 74       // IMG + 2*PAD
#define SCP 520       // sc_bf row stride (bf16), 16B-aligned
#define NTILES 31     // ceil(496/16): padded N for pos-GEMM
#define LN_EPS 1e-5f

typedef __attribute__((ext_vector_type(8))) short bf16x8;
typedef __attribute__((ext_vector_type(4))) float f32x4;
typedef _Float16 h2_t __attribute__((ext_vector_type(2)));

static __device__ __forceinline__ unsigned short f2bf(float f) {
    unsigned u = __float_as_uint(f);
    u += 0x7FFF + ((u >> 16) & 1);          // round-to-nearest-even
    return (unsigned short)(u >> 16);
}
static __device__ __forceinline__ unsigned pkh(float a, float b) {
    _Float16 x = (_Float16)a, y = (_Float16)b;
    return (unsigned)__builtin_bit_cast(unsigned short, x)
         | ((unsigned)__builtin_bit_cast(unsigned short, y) << 16);
}
static __device__ __forceinline__ float dot2(unsigned a, unsigned b, float c) {
#if __has_builtin(__builtin_amdgcn_fdot2)
    return __builtin_amdgcn_fdot2(__builtin_bit_cast(h2_t, a),
                                  __builtin_bit_cast(h2_t, b), c, false);
#else
    h2_t x = __builtin_bit_cast(h2_t, a), y = __builtin_bit_cast(h2_t, b);
    return c + (float)x.x * (float)y.x + (float)x.y * (float)y.y;
#endif
}

// Prologue 1: zero-padded kv -> f16x2 packed: pkvh[(b*PDIM+py)*PDIM+px][64 dw]
__global__ __launch_bounds__(64) void padh_kernel(const float* __restrict__ kv,
                                                  unsigned* __restrict__ pkvh) {
    const int row = blockIdx.x;            // 0 .. 2*74*74-1
    const int b  = row / (PDIM * PDIM);
    const int rr = row - b * PDIM * PDIM;
    const int py = rr / PDIM;
    const int px = rr - py * PDIM;
    const int ky = py - PAD, kx = px - PAD;
    const int t = threadIdx.x;             // chans 2t, 2t+1
    unsigned v = 0;
    if ((unsigned)ky < (unsigned)IMG && (unsigned)kx < (unsigned)IMG) {
        const float2 f = *(const float2*)(kv + (((size_t)b * IMG + ky) * IMG + kx) * DIM + 2 * t);
        v = pkh(f.x, f.y);
    }
    pkvh[(size_t)row * 64 + t] = v;
}

// Prologue 2: W (fp32 [484][128]) -> bf16 MFMA B-frag (as in R11)
__global__ __launch_bounds__(64) void wconv_kernel(const float* __restrict__ w,
                                                   unsigned short* __restrict__ wfrag) {
    const int t    = blockIdx.x & 15;
    const int lane = threadIdx.x;
    const int n    = ((blockIdx.x >> 4) << 4) + (lane & 15);
    const int kb   = t * 32 + ((lane >> 4) << 3);
    unsigned short v[8];
    #pragma unroll
    for (int j = 0; j < 8; ++j) {
        const int k = kb + j;
        v[j] = (k < S_TOT) ? f2bf(w[(size_t)k * DIM + n]) : (unsigned short)0;
    }
    *(uint4*)(wfrag + (((size_t)blockIdx.x * 64 + lane) << 3)) = *(const uint4*)v;
}

// Prologue 3: Ppos[s][c] = (c>>5 == h(s)) ? pos[p(s)][32*r(s)+(c&31)] : 0,
// zero for s>=484, into bf16 B-frag: pfrag[((nt*4+t)*64+lane)*8+j].
__global__ __launch_bounds__(64) void pconv_kernel(const float* __restrict__ pos,
                                                   unsigned short* __restrict__ pfrag) {
    const int idx  = blockIdx.x;           // nt*4 + t, 0..123
    const int nt   = idx >> 2, t = idx & 3;
    const int lane = threadIdx.x;
    const int s    = nt * 16 + (lane & 15);
    const int kb   = t * 32 + ((lane >> 4) << 3);
    unsigned short v[8];
    int p = 0, r = 0, h = 0;
    if (s < S_TOT) { p = s >> 2; r = s & 3; h = s / NN; }
    #pragma unroll
    for (int j = 0; j < 8; ++j) {
        const int c = kb + j;
        unsigned short val = 0;
        if (s < S_TOT && (c >> 5) == h)
            val = f2bf(pos[(size_t)p * DIM + r * 32 + (c & 31)]);
        v[j] = val;
    }
    *(uint4*)(pfrag + (((size_t)idx * 64 + lane) << 3)) = *(const uint4*)v;
}

// Single-arg launch bounds ONLY: (512,8)/(256,8) capped VGPR at 32 and spilled.
__global__ __launch_bounds__(512) void nca_kernel(
    const float* __restrict__ q, const unsigned* __restrict__ pkvh,
    const unsigned short* __restrict__ pfrag, const unsigned short* __restrict__ wfrag,
    const float* __restrict__ bias, const float* __restrict__ gam,
    const float* __restrict__ bet, float* __restrict__ out)
{
    const int tile = blockIdx.x;         // 1024 tiles of 8 pixels along x
    const int pix0 = tile * TILE;
    const int x0 = pix0 & 63;
    const int y  = (pix0 >> 6) & 63;
    const int b  = pix0 >> 12;
    const int tid = threadIdx.x;

    __shared__ float qs[TILE][DIM];               // 4 KB fp32 q / residual
    __shared__ unsigned qh[TILE][64];             // 2 KB f16x2 q
    __shared__ float psc[TILE][NTILES * 16];      // 15.9 KB pos-scores
    __shared__ unsigned short sc_bf[TILE][SCP];   // 8.3 KB bf16 scores
    __shared__ float mlp[TILE][DIM];              // 4 KB MFMA result

    // ---- stage q (coalesced) + zero sc K-pad region [484,520) ----
    for (int i = tid; i < TILE * DIM; i += 512)
        qs[i >> 7][i & 127] = q[(size_t)pix0 * DIM + i];
    for (int i = tid; i < TILE * (SCP - S_TOT); i += 512)
        sc_bf[i / (SCP - S_TOT)][S_TOT + i % (SCP - S_TOT)] = 0;
    __syncthreads();

    // ---- f16 mirror of q (one dword per thread) ----
    qh[tid >> 6][tid & 63] = pkh(qs[tid >> 6][2 * (tid & 63)],
                                 qs[tid >> 6][2 * (tid & 63) + 1]);

    // ---- pos-GEMM: psc[pix][s] = q[pix] . Ppos[s], MFMA 16x16x32 bf16 ----
    // A rows m = lane&15 -> pixel m&7 (rows 8..15 dup); built from global q.
    {
        const int lane = tid & 63, wv = tid >> 6;
        const int m = lane & 15, qd = lane >> 4;
        bf16x8 af[4];
        const float* qg = q + ((size_t)pix0 + (m & 7)) * DIM + qd * 8;
        #pragma unroll
        for (int t = 0; t < 4; ++t) {
            const float4 f0 = *(const float4*)(qg + 32 * t);
            const float4 f1 = *(const float4*)(qg + 32 * t + 4);
            unsigned short a[8] = {f2bf(f0.x), f2bf(f0.y), f2bf(f0.z), f2bf(f0.w),
                                   f2bf(f1.x), f2bf(f1.y), f2bf(f1.z), f2bf(f1.w)};
            af[t] = *(const bf16x8*)a;
        }
        for (int nt = wv; nt < NTILES; nt += 8) {
            const unsigned short* bp = pfrag + (((size_t)(nt * 4) * 64 + lane) << 3);
            f32x4 acc = {0.f, 0.f, 0.f, 0.f};
            #pragma unroll
            for (int t = 0; t < 4; ++t) {
                const bf16x8 bf = *(const bf16x8*)(bp + t * 512);
                acc = __builtin_amdgcn_mfma_f32_16x16x32_bf16(af[t], bf, acc, 0, 0, 0);
            }
            if (qd < 2) {
                #pragma unroll
                for (int reg = 0; reg < 4; ++reg)
                    psc[qd * 4 + reg][nt * 16 + m] = acc[reg];
            }
        }
    }
    __syncthreads();

    // ---- phase A: kv.q via packed-f16 dot2. wave = pixel; 4 16-lane groups
    // = cells p = 4*it+grp. lane l16: chans 8*l16..+7 (uint4 of f16x2);
    // q from qh (register-cached per h); next-iter kv prefetch; adds psc.
    {
        const int pix = tid >> 6;
        const int grp = (tid >> 4) & 3;
        const int l16 = tid & 15;
        const int r   = l16 >> 2;
        const int sub = l16 & 3;
        const int xpix = x0 + pix;

        int p = grp, i = 0, j = grp;
        int rem = 4 * grp + r;
        int h = 0;

        const unsigned* kvb = pkvh + (size_t)b * PDIM * PDIM * 64 + l16 * 4;

        uint4 qv = *(const uint4*)(&qh[pix][sub * 4]);   // h = 0 slice
        const unsigned* kp0 = kvb + (size_t)((y + i) * PDIM + (xpix + j)) * 64;
        uint4 kq = *(const uint4*)kp0;

        for (int it = 0; it < 30; ++it) {
            int pn = p + 4, jn = j + 4, in = i;
            if (jn >= NB) { jn -= NB; ++in; }
            const bool vn = (pn <= 120);
            const int icc = vn ? in : i;
            const int jc  = vn ? jn : j;
            const unsigned* kpn = kvb + (size_t)((y + icc) * PDIM + (xpix + jc)) * 64;
            uint4 nk = *(const uint4*)kpn;

            float t = dot2(kq.x, qv.x, dot2(kq.y, qv.y,
                      dot2(kq.z, qv.z, dot2(kq.w, qv.w, 0.f))));
            t += __shfl_xor(t, 1, 64);
            t += __shfl_xor(t, 2, 64);
            if (sub == 0) {
                const int s = 4 * p + r;
                sc_bf[pix][s] = f2bf(t + psc[pix][s]);
            }

            kq = nk;
            p = pn; i = in; j = jn;
            rem += 16;
            if (rem >= NN) {
                rem -= NN; ++h;
                qv = *(const uint4*)(&qh[pix][h * 16 + sub * 4]);
            }
        }
        if (grp == 0) {            // tail cell p = 120 (regs already loaded)
            float t = dot2(kq.x, qv.x, dot2(kq.y, qv.y,
                      dot2(kq.z, qv.z, dot2(kq.w, qv.w, 0.f))));
            t += __shfl_xor(t, 1, 64);
            t += __shfl_xor(t, 2, 64);
            if (sub == 0)
                sc_bf[pix][480 + r] = f2bf(t + psc[pix][480 + r]);
        }
    }
    __syncthreads();

    // ---- phase B: MFMA MLP (R11): wave = n-tile of 16 channels, K=512 ----
    {
        const int wv   = tid >> 6;
        const int lane = tid & 63;
        const int m    = lane & 15;
        const int quad = lane >> 4;
        const unsigned short* bfr = wfrag + (((size_t)(wv * 16) * 64 + lane) << 3);
        const unsigned short* ap  = &sc_bf[m & 7][quad * 8];
        f32x4 acc = {0.f, 0.f, 0.f, 0.f};
        bf16x8 b0 = *(const bf16x8*)(bfr);
        bf16x8 b1 = *(const bf16x8*)(bfr + 512);
        bf16x8 b2 = *(const bf16x8*)(bfr + 1024);
        bf16x8 b3 = *(const bf16x8*)(bfr + 1536);
        #pragma unroll
        for (int t = 0; t < 16; ++t) {
            const bf16x8 a = *(const bf16x8*)(ap + t * 32);
            bf16x8 bn = b3;
            if (t + 4 < 16) bn = *(const bf16x8*)(bfr + (t + 4) * 512);
            acc = __builtin_amdgcn_mfma_f32_16x16x32_bf16(a, b0, acc, 0, 0, 0);
            b0 = b1; b1 = b2; b2 = b3; b3 = bn;
        }
        if (quad < 2) {
            #pragma unroll
            for (int reg = 0; reg < 4; ++reg)
                mlp[quad * 4 + reg][wv * 16 + m] = acc[reg];
        }
    }
    __syncthreads();

    // ---- epilogue: bias, exact GELU, residual ----
    for (int idx = tid; idx < TILE * DIM; idx += 512) {
        const int pix = idx >> 7, cc = idx & 127;
        const float v = mlp[pix][cc] + bias[cc];
        const float gl = 0.5f * v * (1.f + erff(v * 0.70710678118654752f));
        qs[pix][cc] += gl;               // x = q + gelu(mlp)
    }
    __syncthreads();

    // ---- LayerNorm: wave wid owns pixel wid ----
    {
        const int lane = tid & 63, wid = tid >> 6;
        const float v0 = qs[wid][lane], v1 = qs[wid][lane + 64];
        float sum = v0 + v1;
        #pragma unroll
        for (int off = 1; off < 64; off <<= 1) sum += __shfl_xor(sum, off, 64);
        const float mean = sum * (1.f / 128.f);
        const float d0 = v0 - mean, d1 = v1 - mean;
        float sq = d0 * d0 + d1 * d1;
        #pragma unroll
        for (int off = 1; off < 64; off <<= 1) sq += __shfl_xor(sq, off, 64);
        const float rstd = rsqrtf(sq * (1.f / 128.f) + LN_EPS);
        float* op = out + (size_t)(pix0 + wid) * DIM;
        op[lane]      = d0 * rstd * gam[lane]      + bet[lane];
        op[lane + 64] = d1 * rstd * gam[lane + 64] + bet[lane + 64];
    }
}

// Fallback (fp32, bounds-checked, no workspace) — R10 nopad kernel verbatim.
__global__ __launch_bounds__(512) void nca_kernel_nopad(
    const float* __restrict__ q, const float* __restrict__ kvsrc,
    const float* __restrict__ pos, const float* __restrict__ w,
    const float* __restrict__ bias, const float* __restrict__ gam,
    const float* __restrict__ bet, float* __restrict__ out)
{
    const int tile = blockIdx.x;
    const int pix0 = tile * TILE;
    const int x0 = pix0 & 63;
    const int y  = (pix0 >> 6) & 63;
    const int b  = pix0 >> 12;
    const int tid = threadIdx.x;

    __shared__ float qs[TILE][DIM];
    __shared__ float sc[S_TOT][TILE];
    __shared__ float part[4][TILE][DIM];

    for (int i = tid; i < TILE * DIM; i += 512)
        qs[i >> 7][i & 127] = q[(size_t)pix0 * DIM + i];
    __syncthreads();

    {
        const int pix = tid >> 6;
        const int grp = (tid >> 4) & 3;
        const int l16 = tid & 15;
        const int r   = l16 >> 2;
        const int dq  = 8 * (l16 & 3);
        const int ch  = 8 * l16;
        const int xpix = x0 + pix;
        int p = grp, i = 0, j = grp;
        int h = 0, rem = 4 * grp + r;
        const float* kvb  = kvsrc + (size_t)b * IMG * IMG * DIM + ch;
        const float* posb = pos + ch;
        float4 q0 = *(const float4*)(&qs[pix][dq]);
        float4 q1 = *(const float4*)(&qs[pix][dq + 4]);
        for (int it = 0; it < 31; ++it) {
            if (p <= 120) {
                float4 k0 = make_float4(0.f,0.f,0.f,0.f), k1 = k0;
                const int ky = y + i - PAD, kx = xpix + j - PAD;
                if (((unsigned)ky < (unsigned)IMG) && ((unsigned)kx < (unsigned)IMG)) {
                    const float* kp = kvb + (size_t)(ky * IMG + kx) * DIM;
                    k0 = *(const float4*)(kp);
                    k1 = *(const float4*)(kp + 4);
                }
                const float4 p0 = *(const float4*)(posb + (size_t)p * DIM);
                const float4 p1 = *(const float4*)(posb + (size_t)p * DIM + 4);
                float t = (k0.x + p0.x) * q0.x + (k0.y + p0.y) * q0.y
                        + (k0.z + p0.z) * q0.z + (k0.w + p0.w) * q0.w
                        + (k1.x + p1.x) * q1.x + (k1.y + p1.y) * q1.y
                        + (k1.z + p1.z) * q1.z + (k1.w + p1.w) * q1.w;
                t += __shfl_xor(t, 1, 64);
                t += __shfl_xor(t, 2, 64);
                if ((l16 & 3) == 0) sc[4 * p + r][pix] = t;
            }
            p += 4; j += 4;
            if (j >= NB) { j -= NB; ++i; }
            rem += 16;
            if (rem >= NN) {
                rem -= NN; ++h;
                q0 = *(const float4*)(&qs[pix][h * 32 + dq]);
                q1 = *(const float4*)(&qs[pix][h * 32 + dq + 4]);
            }
        }
    }
    __syncthreads();

    {
        const int l  = tid & 63;
        const int wv = tid >> 6;
        const int g  = wv >> 1;
        const int ph = wv & 1;
        const float* wc  = w + (size_t)(g * NN) * DIM + l;
        const float* scp = &sc[g * NN][ph * 4];
        float a00=0,a01=0,a10=0,a11=0,a20=0,a21=0,a30=0,a31=0;
        #pragma unroll 2
        for (int s = 0; s < NN; ++s) {
            const float4 sv = *(const float4*)(scp + s * 8);
            const float w0 = wc[(size_t)s * DIM];
            const float w1 = wc[(size_t)s * DIM + 64];
            a00 += sv.x * w0; a01 += sv.x * w1;
            a10 += sv.y * w0; a11 += sv.y * w1;
            a20 += sv.z * w0; a21 += sv.z * w1;
            a30 += sv.w * w0; a31 += sv.w * w1;
        }
        const int pb = ph * 4;
        part[g][pb+0][l] = a00; part[g][pb+0][l+64] = a01;
        part[g][pb+1][l] = a10; part[g][pb+1][l+64] = a11;
        part[g][pb+2][l] = a20; part[g][pb+2][l+64] = a21;
        part[g][pb+3][l] = a30; part[g][pb+3][l+64] = a31;
    }
    __syncthreads();

    for (int idx = tid; idx < TILE * DIM; idx += 512) {
        const int pix = idx >> 7, cc = idx & 127;
        float v = part[0][pix][cc] + part[1][pix][cc]
                + part[2][pix][cc] + part[3][pix][cc] + bias[cc];
        const float gl = 0.5f * v * (1.f + erff(v * 0.70710678118654752f));
        qs[pix][cc] += gl;
    }
    __syncthreads();

    {
        const int lane = tid & 63, wid = tid >> 6;
        const float v0 = qs[wid][lane], v1 = qs[wid][lane + 64];
        float sum = v0 + v1;
        #pragma unroll
        for (int off = 1; off < 64; off <<= 1) sum += __shfl_xor(sum, off, 64);
        const float mean = sum * (1.f / 128.f);
        const float d0 = v0 - mean, d1 = v1 - mean;
        float sq = d0 * d0 + d1 * d1;
        #pragma unroll
        for (int off = 1; off < 64; off <<= 1) sq += __shfl_xor(sq, off, 64);
        const float rstd = rsqrtf(sq * (1.f / 128.f) + LN_EPS);
        float* op = out + (size_t)(pix0 + wid) * DIM;
        op[lane]      = d0 * rstd * gam[lane]      + bet[lane];
        op[lane + 64] = d1 * rstd * gam[lane + 64] + bet[lane + 64];
    }
}

extern "C" void kernel_launch(void* const* d_in, const int* in_sizes, int n_in,
                              void* d_out, int out_size, void* d_ws, size_t ws_size,
                              hipStream_t stream) {
    const float* q    = (const float*)d_in[0];
    const float* kv   = (const float*)d_in[1];
    const float* pos  = (const float*)d_in[2];
    const float* w    = (const float*)d_in[3];
    const float* bias = (const float*)d_in[4];
    const float* gam  = (const float*)d_in[5];
    const float* bet  = (const float*)d_in[6];
    float* out = (float*)d_out;

    const int n_blocks = 2 * IMG * IMG / TILE;   // 1024
    const size_t pkvh_bytes  = (size_t)2 * PDIM * PDIM * 64 * sizeof(unsigned);      // 2,803,712
    const size_t wfrag_bytes = (size_t)8 * 16 * 64 * 8 * sizeof(unsigned short);     // 131,072
    const size_t pfrag_bytes = (size_t)NTILES * 4 * 64 * 8 * sizeof(unsigned short); // 126,976

    if (ws_size >= pkvh_bytes + wfrag_bytes + pfrag_bytes) {
        unsigned* pkvh        = (unsigned*)d_ws;
        unsigned short* wfrag = (unsigned short*)((char*)d_ws + pkvh_bytes);
        unsigned short* pfrag = (unsigned short*)((char*)d_ws + pkvh_bytes + wfrag_bytes);
        padh_kernel<<<2 * PDIM * PDIM, 64, 0, stream>>>(kv, pkvh);
        wconv_kernel<<<128, 64, 0, stream>>>(w, wfrag);
        pconv_kernel<<<NTILES * 4, 64, 0, stream>>>(pos, pfrag);
        nca_kernel<<<n_blocks, 512, 0, stream>>>(q, pkvh, pfrag, wfrag, bias, gam, bet, out);
    } else {
        nca_kernel_nopad<<<n_blocks, 512, 0, stream>>>(q, kv, pos, w, bias, gam, bet, out);
    }
}

// Round 13
// 108.589 us; speedup vs baseline: 1.2830x; 1.0430x over previous
//
#include <hip/hip_runtime.h>
#include <math.h>

#define NB 11
#define PAD 5
#define DIM 128
#define NN 121        // NB*NB
#define S_TOT 484     // HEADS*NN
#define IMG 64
#define TILE 8        // pixels per block (x-contiguous)
#define PDIM 74       // IMG + 2*PAD
#define SCP 520       // sc_bf row stride (bf16), 16B-aligned, >= 512
#define NT_A 31       // M-tiles in score GEMM (496 rows >= 484)
#define LN_EPS 1e-5f

typedef __attribute__((ext_vector_type(8))) short bf16x8;
typedef __attribute__((ext_vector_type(4))) float f32x4;

static __device__ __forceinline__ unsigned short f2bf(float f) {
    unsigned u = __float_as_uint(f);
    u += 0x7FFF + ((u >> 16) & 1);          // round-to-nearest-even
    return (unsigned short)(u >> 16);
}

// Prologue 1: kv fp32 -> bf16, zero-padded: pkvb[(b*PDIM+py)*PDIM+px][128]
__global__ __launch_bounds__(64) void padb_kernel(const float* __restrict__ kv,
                                                  unsigned short* __restrict__ pkvb) {
    const int row = blockIdx.x;            // 0 .. 2*74*74-1
    const int b  = row / (PDIM * PDIM);
    const int rr = row - b * PDIM * PDIM;
    const int py = rr / PDIM;
    const int px = rr - py * PDIM;
    const int ky = py - PAD, kx = px - PAD;
    const int t = threadIdx.x;             // chans 2t, 2t+1
    unsigned v = 0;
    if ((unsigned)ky < (unsigned)IMG && (unsigned)kx < (unsigned)IMG) {
        const float2 f = *(const float2*)(kv + (((size_t)b * IMG + ky) * IMG + kx) * DIM + 2 * t);
        v = (unsigned)f2bf(f.x) | ((unsigned)f2bf(f.y) << 16);
    }
    *(unsigned*)(pkvb + (size_t)row * DIM + 2 * t) = v;
}

// Prologue 2: W (fp32 [484][128]) -> bf16 MFMA B-frag (zero for k>=484)
__global__ __launch_bounds__(64) void wconv_kernel(const float* __restrict__ w,
                                                   unsigned short* __restrict__ wfrag) {
    const int t    = blockIdx.x & 15;
    const int lane = threadIdx.x;
    const int n    = ((blockIdx.x >> 4) << 4) + (lane & 15);
    const int kb   = t * 32 + ((lane >> 4) << 3);
    unsigned short v[8];
    #pragma unroll
    for (int j = 0; j < 8; ++j) {
        const int k = kb + j;
        v[j] = (k < S_TOT) ? f2bf(w[(size_t)k * DIM + n]) : (unsigned short)0;
    }
    *(uint4*)(wfrag + (((size_t)blockIdx.x * 64 + lane) << 3)) = *(const uint4*)v;
}

// Prologue 3: pos -> bf16 MFMA A-frag per M-tile of the score GEMM:
// posA[(mt*64+lane)*8+j] = pos4[s=16mt+(lane&15)][ (lane>>4)*8+j ],
// pos4[s][d] = pos[s>>2][32*(s&3)+d]; zero rows with p>120 (s>=484).
__global__ __launch_bounds__(64) void pconvA_kernel(const float* __restrict__ pos,
                                                    unsigned short* __restrict__ posA) {
    const int mt   = blockIdx.x;           // 0..30
    const int lane = threadIdx.x;
    const int m    = lane & 15, quad = lane >> 4;
    const int p    = 4 * mt + (m >> 2);
    const int r    = m & 3;
    unsigned short v[8];
    #pragma unroll
    for (int j = 0; j < 8; ++j)
        v[j] = (p <= 120) ? f2bf(pos[(size_t)p * DIM + 32 * r + 8 * quad + j])
                          : (unsigned short)0;
    *(uint4*)(posA + (((size_t)mt * 64 + lane) << 3)) = *(const uint4*)v;
}

// Single-arg launch bounds ONLY: (512,8)/(256,8) capped VGPR at 32 and spilled.
__global__ __launch_bounds__(512) void nca_kernel(
    const float* __restrict__ q, const unsigned short* __restrict__ pkvb,
    const unsigned short* __restrict__ posA, const unsigned short* __restrict__ wfrag,
    const float* __restrict__ bias, const float* __restrict__ gam,
    const float* __restrict__ bet, float* __restrict__ out)
{
    const int tile = blockIdx.x;         // 1024 tiles of 8 pixels along x
    const int pix0 = tile * TILE;
    const int x0 = pix0 & 63;
    const int y  = (pix0 >> 6) & 63;
    const int b  = pix0 >> 12;
    const int tid = threadIdx.x;

    __shared__ float qs[TILE][DIM];               // 4 KB fp32 q / residual
    __shared__ unsigned short sc_bf[TILE][SCP];   // 8.3 KB bf16 scores
    __shared__ float mlp[TILE][DIM];              // 4 KB MFMA result

    // ---- stage q + zero sc K-pad [484,520) (no barrier needed before A:
    // phase A reads no LDS; writes are disjoint from the pad region) ----
    for (int i = tid; i < TILE * DIM; i += 512)
        qs[i >> 7][i & 127] = q[(size_t)pix0 * DIM + i];
    for (int i = tid; i < TILE * (SCP - S_TOT); i += 512)
        sc_bf[i / (SCP - S_TOT)][S_TOT + i % (SCP - S_TOT)] = 0;

    // ---- phase A: score GEMM. wave = pixel. Per pixel:
    // D[s][n] = (K4 + pos4)[s][:] . q[32*(n&3) + :32], MFMA 16x16x32 bf16,
    // 31 M-tiles x 2 chained MFMAs. score[s] = D[s][h], h=(271*s)>>15.
    // A lane m: cell p = 4mt+(m>>2), chans 32*(m&3)+8*quad. kv + posA
    // streams 1-tile-ahead prefetched; extraction: lanes with (lane&15)==h.
    {
        const int pix  = tid >> 6;
        const int lane = tid & 63;
        const int m    = lane & 15, quad = lane >> 4;
        const int coff = 32 * (m & 3) + 8 * quad;   // A chan offset; ALSO B q offset

        // B-frag: q[pix] slice (cols n>=4 duplicate n&3 -> unused D cols)
        const float* qb = q + ((size_t)(pix0 + pix)) * DIM + coff;
        const float4 f0 = *(const float4*)qb;
        const float4 f1 = *(const float4*)(qb + 4);
        unsigned short bq_[8] = {f2bf(f0.x), f2bf(f0.y), f2bf(f0.z), f2bf(f0.w),
                                 f2bf(f1.x), f2bf(f1.y), f2bf(f1.z), f2bf(f1.w)};
        const bf16x8 bq = *(const bf16x8*)bq_;

        int p = m >> 2, ii = 0, jj = p;             // cell index (i,j), p = 11i+j
        const unsigned short* kvb = pkvb
            + ((size_t)((b * PDIM + y) * PDIM) + (x0 + pix)) * DIM + coff;
        const unsigned short* pp = posA + ((size_t)lane << 3);

        bf16x8 ak = *(const bf16x8*)(kvb);          // tile 0: (ii=0, jj=p)
        if (jj) ak = *(const bf16x8*)(kvb + jj * DIM);
        bf16x8 ap = *(const bf16x8*)(pp);

        for (int t = 0; t < NT_A; ++t) {
            // prefetch tile t+1 (clamped)
            int pn = p + 4, jn = jj + 4, in = ii;
            if (jn >= NB) { jn -= NB; ++in; }
            const int ic = (pn > 120) ? 10 : in;
            const int jc = (pn > 120) ? 10 : jn;
            const bf16x8 nk = *(const bf16x8*)(kvb + (ic * PDIM + jc) * DIM);
            const int tn = (t + 1 < NT_A) ? (t + 1) : t;
            const bf16x8 np = *(const bf16x8*)(pp + tn * 512);

            f32x4 acc = {0.f, 0.f, 0.f, 0.f};
            acc = __builtin_amdgcn_mfma_f32_16x16x32_bf16(ak, bq, acc, 0, 0, 0);
            acc = __builtin_amdgcn_mfma_f32_16x16x32_bf16(ap, bq, acc, 0, 0, 0);

            // extraction: row s = 16t + quad*4 + reg, need col m == h(s)
            const int sbase = 16 * t + quad * 4;
            #pragma unroll
            for (int reg = 0; reg < 4; ++reg) {
                const int s = sbase + reg;
                const int h = (271 * s) >> 15;      // s/121, exact for s<512
                if (m == h && s < S_TOT) sc_bf[pix][s] = f2bf(acc[reg]);
            }
            ak = nk; ap = np; p = pn; ii = in; jj = jn;
        }
    }
    __syncthreads();

    // ---- phase B: MFMA MLP (R11/12): wave = n-tile of 16 channels, K=512 ----
    {
        const int wv   = tid >> 6;
        const int lane = tid & 63;
        const int m    = lane & 15;
        const int quad = lane >> 4;
        const unsigned short* bfr = wfrag + (((size_t)(wv * 16) * 64 + lane) << 3);
        const unsigned short* ap  = &sc_bf[m & 7][quad * 8];
        f32x4 acc = {0.f, 0.f, 0.f, 0.f};
        bf16x8 b0 = *(const bf16x8*)(bfr);
        bf16x8 b1 = *(const bf16x8*)(bfr + 512);
        bf16x8 b2 = *(const bf16x8*)(bfr + 1024);
        bf16x8 b3 = *(const bf16x8*)(bfr + 1536);
        #pragma unroll
        for (int t = 0; t < 16; ++t) {
            const bf16x8 a = *(const bf16x8*)(ap + t * 32);
            bf16x8 bn = b3;
            if (t + 4 < 16) bn = *(const bf16x8*)(bfr + (t + 4) * 512);
            acc = __builtin_amdgcn_mfma_f32_16x16x32_bf16(a, b0, acc, 0, 0, 0);
            b0 = b1; b1 = b2; b2 = b3; b3 = bn;
        }
        if (quad < 2) {
            #pragma unroll
            for (int reg = 0; reg < 4; ++reg)
                mlp[quad * 4 + reg][wv * 16 + m] = acc[reg];
        }
    }
    __syncthreads();

    // ---- epilogue: bias, exact GELU, residual ----
    for (int idx = tid; idx < TILE * DIM; idx += 512) {
        const int pix = idx >> 7, cc = idx & 127;
        const float v = mlp[pix][cc] + bias[cc];
        const float gl = 0.5f * v * (1.f + erff(v * 0.70710678118654752f));
        qs[pix][cc] += gl;               // x = q + gelu(mlp)
    }
    __syncthreads();

    // ---- LayerNorm: wave wid owns pixel wid ----
    {
        const int lane = tid & 63, wid = tid >> 6;
        const float v0 = qs[wid][lane], v1 = qs[wid][lane + 64];
        float sum = v0 + v1;
        #pragma unroll
        for (int off = 1; off < 64; off <<= 1) sum += __shfl_xor(sum, off, 64);
        const float mean = sum * (1.f / 128.f);
        const float d0 = v0 - mean, d1 = v1 - mean;
        float sq = d0 * d0 + d1 * d1;
        #pragma unroll
        for (int off = 1; off < 64; off <<= 1) sq += __shfl_xor(sq, off, 64);
        const float rstd = rsqrtf(sq * (1.f / 128.f) + LN_EPS);
        float* op = out + (size_t)(pix0 + wid) * DIM;
        op[lane]      = d0 * rstd * gam[lane]      + bet[lane];
        op[lane + 64] = d1 * rstd * gam[lane + 64] + bet[lane + 64];
    }
}

// Fallback (fp32, bounds-checked, no workspace).
__global__ __launch_bounds__(512) void nca_kernel_nopad(
    const float* __restrict__ q, const float* __restrict__ kvsrc,
    const float* __restrict__ pos, const float* __restrict__ w,
    const float* __restrict__ bias, const float* __restrict__ gam,
    const float* __restrict__ bet, float* __restrict__ out)
{
    const int tile = blockIdx.x;
    const int pix0 = tile * TILE;
    const int x0 = pix0 & 63;
    const int y  = (pix0 >> 6) & 63;
    const int b  = pix0 >> 12;
    const int tid = threadIdx.x;

    __shared__ float qs[TILE][DIM];
    __shared__ float sc[S_TOT][TILE];
    __shared__ float part[4][TILE][DIM];

    for (int i = tid; i < TILE * DIM; i += 512)
        qs[i >> 7][i & 127] = q[(size_t)pix0 * DIM + i];
    __syncthreads();

    {
        const int pix = tid >> 6;
        const int grp = (tid >> 4) & 3;
        const int l16 = tid & 15;
        const int r   = l16 >> 2;
        const int dq  = 8 * (l16 & 3);
        const int ch  = 8 * l16;
        const int xpix = x0 + pix;
        int p = grp, i = 0, j = grp;
        int h = 0, rem = 4 * grp + r;
        const float* kvb  = kvsrc + (size_t)b * IMG * IMG * DIM + ch;
        const float* posb = pos + ch;
        float4 q0 = *(const float4*)(&qs[pix][dq]);
        float4 q1 = *(const float4*)(&qs[pix][dq + 4]);
        for (int it = 0; it < 31; ++it) {
            if (p <= 120) {
                float4 k0 = make_float4(0.f,0.f,0.f,0.f), k1 = k0;
                const int ky = y + i - PAD, kx = xpix + j - PAD;
                if (((unsigned)ky < (unsigned)IMG) && ((unsigned)kx < (unsigned)IMG)) {
                    const float* kp = kvb + (size_t)(ky * IMG + kx) * DIM;
                    k0 = *(const float4*)(kp);
                    k1 = *(const float4*)(kp + 4);
                }
                const float4 p0 = *(const float4*)(posb + (size_t)p * DIM);
                const float4 p1 = *(const float4*)(posb + (size_t)p * DIM + 4);
                float t = (k0.x + p0.x) * q0.x + (k0.y + p0.y) * q0.y
                        + (k0.z + p0.z) * q0.z + (k0.w + p0.w) * q0.w
                        + (k1.x + p1.x) * q1.x + (k1.y + p1.y) * q1.y
                        + (k1.z + p1.z) * q1.z + (k1.w + p1.w) * q1.w;
                t += __shfl_xor(t, 1, 64);
                t += __shfl_xor(t, 2, 64);
                if ((l16 & 3) == 0) sc[4 * p + r][pix] = t;
            }
            p += 4; j += 4;
            if (j >= NB) { j -= NB; ++i; }
            rem += 16;
            if (rem >= NN) {
                rem -= NN; ++h;
                q0 = *(const float4*)(&qs[pix][h * 32 + dq]);
                q1 = *(const float4*)(&qs[pix][h * 32 + dq + 4]);
            }
        }
    }
    __syncthreads();

    {
        const int l  = tid & 63;
        const int wv = tid >> 6;
        const int g  = wv >> 1;
        const int ph = wv & 1;
        const float* wc  = w + (size_t)(g * NN) * DIM + l;
        const float* scp = &sc[g * NN][ph * 4];
        float a00=0,a01=0,a10=0,a11=0,a20=0,a21=0,a30=0,a31=0;
        #pragma unroll 2
        for (int s = 0; s < NN; ++s) {
            const float4 sv = *(const float4*)(scp + s * 8);
            const float w0 = wc[(size_t)s * DIM];
            const float w1 = wc[(size_t)s * DIM + 64];
            a00 += sv.x * w0; a01 += sv.x * w1;
            a10 += sv.y * w0; a11 += sv.y * w1;
            a20 += sv.z * w0; a21 += sv.z * w1;
            a30 += sv.w * w0; a31 += sv.w * w1;
        }
        const int pb = ph * 4;
        part[g][pb+0][l] = a00; part[g][pb+0][l+64] = a01;
        part[g][pb+1][l] = a10; part[g][pb+1][l+64] = a11;
        part[g][pb+2][l] = a20; part[g][pb+2][l+64] = a21;
        part[g][pb+3][l] = a30; part[g][pb+3][l+64] = a31;
    }
    __syncthreads();

    for (int idx = tid; idx < TILE * DIM; idx += 512) {
        const int pix = idx >> 7, cc = idx & 127;
        float v = part[0][pix][cc] + part[1][pix][cc]
                + part[2][pix][cc] + part[3][pix][cc] + bias[cc];
        const float gl = 0.5f * v * (1.f + erff(v * 0.70710678118654752f));
        qs[pix][cc] += gl;
    }
    __syncthreads();

    {
        const int lane = tid & 63, wid = tid >> 6;
        const float v0 = qs[wid][lane], v1 = qs[wid][lane + 64];
        float sum = v0 + v1;
        #pragma unroll
        for (int off = 1; off < 64; off <<= 1) sum += __shfl_xor(sum, off, 64);
        const float mean = sum * (1.f / 128.f);
        const float d0 = v0 - mean, d1 = v1 - mean;
        float sq = d0 * d0 + d1 * d1;
        #pragma unroll
        for (int off = 1; off < 64; off <<= 1) sq += __shfl_xor(sq, off, 64);
        const float rstd = rsqrtf(sq * (1.f / 128.f) + LN_EPS);
        float* op = out + (size_t)(pix0 + wid) * DIM;
        op[lane]      = d0 * rstd * gam[lane]      + bet[lane];
        op[lane + 64] = d1 * rstd * gam[lane + 64] + bet[lane + 64];
    }
}

extern "C" void kernel_launch(void* const* d_in, const int* in_sizes, int n_in,
                              void* d_out, int out_size, void* d_ws, size_t ws_size,
                              hipStream_t stream) {
    const float* q    = (const float*)d_in[0];
    const float* kv   = (const float*)d_in[1];
    const float* pos  = (const float*)d_in[2];
    const float* w    = (const float*)d_in[3];
    const float* bias = (const float*)d_in[4];
    const float* gam  = (const float*)d_in[5];
    const float* bet  = (const float*)d_in[6];
    float* out = (float*)d_out;

    const int n_blocks = 2 * IMG * IMG / TILE;   // 1024
    const size_t pkvb_bytes  = (size_t)2 * PDIM * PDIM * DIM * sizeof(unsigned short); // 2,803,712
    const size_t wfrag_bytes = (size_t)8 * 16 * 64 * 8 * sizeof(unsigned short);       // 131,072
    const size_t posA_bytes  = (size_t)NT_A * 64 * 8 * sizeof(unsigned short);         // 31,744

    if (ws_size >= pkvb_bytes + wfrag_bytes + posA_bytes) {
        unsigned short* pkvb  = (unsigned short*)d_ws;
        unsigned short* wfrag = (unsigned short*)((char*)d_ws + pkvb_bytes);
        unsigned short* posA  = (unsigned short*)((char*)d_ws + pkvb_bytes + wfrag_bytes);
        padb_kernel<<<2 * PDIM * PDIM, 64, 0, stream>>>(kv, pkvb);
        wconv_kernel<<<128, 64, 0, stream>>>(w, wfrag);
        pconvA_kernel<<<NT_A, 64, 0, stream>>>(pos, posA);
        nca_kernel<<<n_blocks, 512, 0, stream>>>(q, pkvb, posA, wfrag, bias, gam, bet, out);
    } else {
        nca_kernel_nopad<<<n_blocks, 512, 0, stream>>>(q, kv, pos, w, bias, gam, bet, out);
    }
}

// Round 14
// 104.938 us; speedup vs baseline: 1.3276x; 1.0348x over previous
//
#include <hip/hip_runtime.h>
#include <math.h>

#define NB 11
#define PAD 5
#define DIM 128
#define NN 121        // NB*NB
#define S_TOT 484     // HEADS*NN
#define IMG 64
#define TILE 8        // pixels per block (x-contiguous)
#define PDIM 74       // IMG + 2*PAD
#define SCP 520       // sc_bf row stride (bf16), 16B-aligned, >= 512
#define NT_A 31       // M-tiles in score GEMM (496 rows >= 484)
#define NPAD (2 * PDIM * PDIM)   // 10952 pad-copy blocks
#define LN_EPS 1e-5f

typedef __attribute__((ext_vector_type(8))) short bf16x8;
typedef __attribute__((ext_vector_type(4))) float f32x4;

static __device__ __forceinline__ unsigned short f2bf(float f) {
    unsigned u = __float_as_uint(f);
    u += 0x7FFF + ((u >> 16) & 1);          // round-to-nearest-even
    return (unsigned short)(u >> 16);
}

// Fused prologue: blocks [0,NPAD) pad+bf16 kv; [NPAD,NPAD+128) W B-frag;
// [NPAD+128, NPAD+128+31) pos A-frag.
__global__ __launch_bounds__(64) void prep_kernel(
    const float* __restrict__ kv, const float* __restrict__ w,
    const float* __restrict__ pos, unsigned short* __restrict__ pkvb,
    unsigned short* __restrict__ wfrag, unsigned short* __restrict__ posA)
{
    const int blk  = blockIdx.x;
    const int lane = threadIdx.x;
    if (blk < NPAD) {
        // kv fp32 -> bf16, zero-padded: pkvb[(b*PDIM+py)*PDIM+px][128]
        const int b  = blk / (PDIM * PDIM);
        const int rr = blk - b * PDIM * PDIM;
        const int py = rr / PDIM;
        const int px = rr - py * PDIM;
        const int ky = py - PAD, kx = px - PAD;
        unsigned v = 0;
        if ((unsigned)ky < (unsigned)IMG && (unsigned)kx < (unsigned)IMG) {
            const float2 f = *(const float2*)(kv + (((size_t)b * IMG + ky) * IMG + kx) * DIM + 2 * lane);
            v = (unsigned)f2bf(f.x) | ((unsigned)f2bf(f.y) << 16);
        }
        *(unsigned*)(pkvb + (size_t)blk * DIM + 2 * lane) = v;
    } else if (blk < NPAD + 128) {
        // W (fp32 [484][128]) -> bf16 MFMA B-frag (zero for k>=484)
        const int idx = blk - NPAD;
        const int t   = idx & 15;
        const int n   = ((idx >> 4) << 4) + (lane & 15);
        const int kb  = t * 32 + ((lane >> 4) << 3);
        unsigned short v[8];
        #pragma unroll
        for (int j = 0; j < 8; ++j) {
            const int k = kb + j;
            v[j] = (k < S_TOT) ? f2bf(w[(size_t)k * DIM + n]) : (unsigned short)0;
        }
        *(uint4*)(wfrag + (((size_t)idx * 64 + lane) << 3)) = *(const uint4*)v;
    } else {
        // pos -> bf16 MFMA A-frag per score-GEMM M-tile:
        // posA[(mt*64+lane)*8+j] = pos4[16mt+(lane&15)][(lane>>4)*8+j],
        // pos4[s][d] = pos[s>>2][32*(s&3)+d]; zero rows p>120.
        const int mt   = blk - NPAD - 128;
        const int m    = lane & 15, quad = lane >> 4;
        const int p    = 4 * mt + (m >> 2);
        const int r    = m & 3;
        unsigned short v[8];
        #pragma unroll
        for (int j = 0; j < 8; ++j)
            v[j] = (p <= 120) ? f2bf(pos[(size_t)p * DIM + 32 * r + 8 * quad + j])
                              : (unsigned short)0;
        *(uint4*)(posA + (((size_t)mt * 64 + lane) << 3)) = *(const uint4*)v;
    }
}

// Single-arg launch bounds ONLY: (512,8)/(256,8) capped VGPR at 32 and spilled.
__global__ __launch_bounds__(512) void nca_kernel(
    const float* __restrict__ q, const unsigned short* __restrict__ pkvb,
    const unsigned short* __restrict__ posA, const unsigned short* __restrict__ wfrag,
    const float* __restrict__ bias, const float* __restrict__ gam,
    const float* __restrict__ bet, float* __restrict__ out)
{
    const int tile = blockIdx.x;         // 1024 tiles of 8 pixels along x
    const int pix0 = tile * TILE;
    const int x0 = pix0 & 63;
    const int y  = (pix0 >> 6) & 63;
    const int b  = pix0 >> 12;
    const int tid = threadIdx.x;

    __shared__ float qs[TILE][DIM];                          // 4 KB
    __shared__ __align__(16) unsigned short sc_bf[TILE][SCP];// 8.3 KB bf16 scores
    __shared__ float mlp[TILE][DIM];                         // 4 KB

    // ---- stage q; zero only sc rows [496,512) (read by phase B's K=512 but
    // never written; rows 484..495 get finite junk * zero-W = 0). No barrier
    // needed before A: regions disjoint. ----
    for (int i = tid; i < TILE * DIM; i += 512)
        qs[i >> 7][i & 127] = q[(size_t)pix0 * DIM + i];
    if (tid < TILE * 16)
        sc_bf[tid >> 4][496 + (tid & 15)] = 0;

    // ---- phase A: score GEMM. wave = pixel. D[s][n] = (K4+pos4)[s]. q-slice,
    // 31 M-tiles x 2 chained MFMA 16x16x32 bf16; score[s] = D[s][h(s)],
    // h = (271*s)>>15 (= s/121 exact for s<512). Extraction: packed b64 when
    // h uniform over the quad's 4 rows (all but 3 boundary quads). ----
    {
        const int pix  = tid >> 6;
        const int lane = tid & 63;
        const int m    = lane & 15, quad = lane >> 4;
        const int coff = 32 * (m & 3) + 8 * quad;   // A chan offset = B q offset

        const float* qb = q + ((size_t)(pix0 + pix)) * DIM + coff;
        const float4 f0 = *(const float4*)qb;
        const float4 f1 = *(const float4*)(qb + 4);
        unsigned short bq_[8] = {f2bf(f0.x), f2bf(f0.y), f2bf(f0.z), f2bf(f0.w),
                                 f2bf(f1.x), f2bf(f1.y), f2bf(f1.z), f2bf(f1.w)};
        const bf16x8 bq = *(const bf16x8*)bq_;

        int p = m >> 2, ii = 0, jj = p;             // cell (i,j), p = 11i+j
        const unsigned short* kvb = pkvb
            + ((size_t)((b * PDIM + y) * PDIM) + (x0 + pix)) * DIM + coff;
        const unsigned short* pp = posA + ((size_t)lane << 3);

        bf16x8 ak = *(const bf16x8*)(kvb + jj * DIM);
        bf16x8 ap = *(const bf16x8*)(pp);

        for (int t = 0; t < NT_A; ++t) {
            // prefetch tile t+1 (clamped)
            int pn = p + 4, jn = jj + 4, in = ii;
            if (jn >= NB) { jn -= NB; ++in; }
            const int ic = (pn > 120) ? 10 : in;
            const int jc = (pn > 120) ? 10 : jn;
            const bf16x8 nk = *(const bf16x8*)(kvb + (ic * PDIM + jc) * DIM);
            const int tn = (t + 1 < NT_A) ? (t + 1) : t;
            const bf16x8 np = *(const bf16x8*)(pp + tn * 512);

            f32x4 acc = {0.f, 0.f, 0.f, 0.f};
            acc = __builtin_amdgcn_mfma_f32_16x16x32_bf16(ak, bq, acc, 0, 0, 0);
            acc = __builtin_amdgcn_mfma_f32_16x16x32_bf16(ap, bq, acc, 0, 0, 0);

            const int sbase = 16 * t + quad * 4;    // rows sbase..sbase+3, col m
            const int h0 = (271 * sbase) >> 15;
            const int h3 = (271 * (sbase + 3)) >> 15;
            if (h0 == h3) {
                if (m == h0) {
                    unsigned short v[4] = {f2bf(acc[0]), f2bf(acc[1]),
                                           f2bf(acc[2]), f2bf(acc[3])};
                    *(uint2*)&sc_bf[pix][sbase] = *(const uint2*)v;
                }
            } else {                                // 3 boundary quads only
                #pragma unroll
                for (int reg = 0; reg < 4; ++reg) {
                    const int s = sbase + reg;
                    const int h = (271 * s) >> 15;
                    if (m == h) sc_bf[pix][s] = f2bf(acc[reg]);
                }
            }
            ak = nk; ap = np; p = pn; ii = in; jj = jn;
        }
    }
    __syncthreads();

    // ---- phase B: MFMA MLP: wave = n-tile of 16 channels, K=512 ----
    {
        const int wv   = tid >> 6;
        const int lane = tid & 63;
        const int m    = lane & 15;
        const int quad = lane >> 4;
        const unsigned short* bfr = wfrag + (((size_t)(wv * 16) * 64 + lane) << 3);
        const unsigned short* ap  = &sc_bf[m & 7][quad * 8];
        f32x4 acc = {0.f, 0.f, 0.f, 0.f};
        bf16x8 b0 = *(const bf16x8*)(bfr);
        bf16x8 b1 = *(const bf16x8*)(bfr + 512);
        bf16x8 b2 = *(const bf16x8*)(bfr + 1024);
        bf16x8 b3 = *(const bf16x8*)(bfr + 1536);
        #pragma unroll
        for (int t = 0; t < 16; ++t) {
            const bf16x8 a = *(const bf16x8*)(ap + t * 32);
            bf16x8 bn = b3;
            if (t + 4 < 16) bn = *(const bf16x8*)(bfr + (t + 4) * 512);
            acc = __builtin_amdgcn_mfma_f32_16x16x32_bf16(a, b0, acc, 0, 0, 0);
            b0 = b1; b1 = b2; b2 = b3; b3 = bn;
        }
        if (quad < 2) {
            #pragma unroll
            for (int reg = 0; reg < 4; ++reg)
                mlp[quad * 4 + reg][wv * 16 + m] = acc[reg];
        }
    }
    __syncthreads();

    // ---- epilogue: bias, exact GELU, residual ----
    for (int idx = tid; idx < TILE * DIM; idx += 512) {
        const int pix = idx >> 7, cc = idx & 127;
        const float v = mlp[pix][cc] + bias[cc];
        const float gl = 0.5f * v * (1.f + erff(v * 0.70710678118654752f));
        qs[pix][cc] += gl;               // x = q + gelu(mlp)
    }
    __syncthreads();

    // ---- LayerNorm: wave wid owns pixel wid ----
    {
        const int lane = tid & 63, wid = tid >> 6;
        const float v0 = qs[wid][lane], v1 = qs[wid][lane + 64];
        float sum = v0 + v1;
        #pragma unroll
        for (int off = 1; off < 64; off <<= 1) sum += __shfl_xor(sum, off, 64);
        const float mean = sum * (1.f / 128.f);
        const float d0 = v0 - mean, d1 = v1 - mean;
        float sq = d0 * d0 + d1 * d1;
        #pragma unroll
        for (int off = 1; off < 64; off <<= 1) sq += __shfl_xor(sq, off, 64);
        const float rstd = rsqrtf(sq * (1.f / 128.f) + LN_EPS);
        float* op = out + (size_t)(pix0 + wid) * DIM;
        op[lane]      = d0 * rstd * gam[lane]      + bet[lane];
        op[lane + 64] = d1 * rstd * gam[lane + 64] + bet[lane + 64];
    }
}

// Fallback (fp32, bounds-checked, no workspace).
__global__ __launch_bounds__(512) void nca_kernel_nopad(
    const float* __restrict__ q, const float* __restrict__ kvsrc,
    const float* __restrict__ pos, const float* __restrict__ w,
    const float* __restrict__ bias, const float* __restrict__ gam,
    const float* __restrict__ bet, float* __restrict__ out)
{
    const int tile = blockIdx.x;
    const int pix0 = tile * TILE;
    const int x0 = pix0 & 63;
    const int y  = (pix0 >> 6) & 63;
    const int b  = pix0 >> 12;
    const int tid = threadIdx.x;

    __shared__ float qs[TILE][DIM];
    __shared__ float sc[S_TOT][TILE];
    __shared__ float part[4][TILE][DIM];

    for (int i = tid; i < TILE * DIM; i += 512)
        qs[i >> 7][i & 127] = q[(size_t)pix0 * DIM + i];
    __syncthreads();

    {
        const int pix = tid >> 6;
        const int grp = (tid >> 4) & 3;
        const int l16 = tid & 15;
        const int r   = l16 >> 2;
        const int dq  = 8 * (l16 & 3);
        const int ch  = 8 * l16;
        const int xpix = x0 + pix;
        int p = grp, i = 0, j = grp;
        int h = 0, rem = 4 * grp + r;
        const float* kvb  = kvsrc + (size_t)b * IMG * IMG * DIM + ch;
        const float* posb = pos + ch;
        float4 q0 = *(const float4*)(&qs[pix][dq]);
        float4 q1 = *(const float4*)(&qs[pix][dq + 4]);
        for (int it = 0; it < 31; ++it) {
            if (p <= 120) {
                float4 k0 = make_float4(0.f,0.f,0.f,0.f), k1 = k0;
                const int ky = y + i - PAD, kx = xpix + j - PAD;
                if (((unsigned)ky < (unsigned)IMG) && ((unsigned)kx < (unsigned)IMG)) {
                    const float* kp = kvb + (size_t)(ky * IMG + kx) * DIM;
                    k0 = *(const float4*)(kp);
                    k1 = *(const float4*)(kp + 4);
                }
                const float4 p0 = *(const float4*)(posb + (size_t)p * DIM);
                const float4 p1 = *(const float4*)(posb + (size_t)p * DIM + 4);
                float t = (k0.x + p0.x) * q0.x + (k0.y + p0.y) * q0.y
                        + (k0.z + p0.z) * q0.z + (k0.w + p0.w) * q0.w
                        + (k1.x + p1.x) * q1.x + (k1.y + p1.y) * q1.y
                        + (k1.z + p1.z) * q1.z + (k1.w + p1.w) * q1.w;
                t += __shfl_xor(t, 1, 64);
                t += __shfl_xor(t, 2, 64);
                if ((l16 & 3) == 0) sc[4 * p + r][pix] = t;
            }
            p += 4; j += 4;
            if (j >= NB) { j -= NB; ++i; }
            rem += 16;
            if (rem >= NN) {
                rem -= NN; ++h;
                q0 = *(const float4*)(&qs[pix][h * 32 + dq]);
                q1 = *(const float4*)(&qs[pix][h * 32 + dq + 4]);
            }
        }
    }
    __syncthreads();

    {
        const int l  = tid & 63;
        const int wv = tid >> 6;
        const int g  = wv >> 1;
        const int ph = wv & 1;
        const float* wc  = w + (size_t)(g * NN) * DIM + l;
        const float* scp = &sc[g * NN][ph * 4];
        float a00=0,a01=0,a10=0,a11=0,a20=0,a21=0,a30=0,a31=0;
        #pragma unroll 2
        for (int s = 0; s < NN; ++s) {
            const float4 sv = *(const float4*)(scp + s * 8);
            const float w0 = wc[(size_t)s * DIM];
            const float w1 = wc[(size_t)s * DIM + 64];
            a00 += sv.x * w0; a01 += sv.x * w1;
            a10 += sv.y * w0; a11 += sv.y * w1;
            a20 += sv.z * w0; a21 += sv.z * w1;
            a30 += sv.w * w0; a31 += sv.w * w1;
        }
        const int pb = ph * 4;
        part[g][pb+0][l] = a00; part[g][pb+0][l+64] = a01;
        part[g][pb+1][l] = a10; part[g][pb+1][l+64] = a11;
        part[g][pb+2][l] = a20; part[g][pb+2][l+64] = a21;
        part[g][pb+3][l] = a30; part[g][pb+3][l+64] = a31;
    }
    __syncthreads();

    for (int idx = tid; idx < TILE * DIM; idx += 512) {
        const int pix = idx >> 7, cc = idx & 127;
        float v = part[0][pix][cc] + part[1][pix][cc]
                + part[2][pix][cc] + part[3][pix][cc] + bias[cc];
        const float gl = 0.5f * v * (1.f + erff(v * 0.70710678118654752f));
        qs[pix][cc] += gl;
    }
    __syncthreads();

    {
        const int lane = tid & 63, wid = tid >> 6;
        const float v0 = qs[wid][lane], v1 = qs[wid][lane + 64];
        float sum = v0 + v1;
        #pragma unroll
        for (int off = 1; off < 64; off <<= 1) sum += __shfl_xor(sum, off, 64);
        const float mean = sum * (1.f / 128.f);
        const float d0 = v0 - mean, d1 = v1 - mean;
        float sq = d0 * d0 + d1 * d1;
        #pragma unroll
        for (int off = 1; off < 64; off <<= 1) sq += __shfl_xor(sq, off, 64);
        const float rstd = rsqrtf(sq * (1.f / 128.f) + LN_EPS);
        float* op = out + (size_t)(pix0 + wid) * DIM;
        op[lane]      = d0 * rstd * gam[lane]      + bet[lane];
        op[lane + 64] = d1 * rstd * gam[lane + 64] + bet[lane + 64];
    }
}

extern "C" void kernel_launch(void* const* d_in, const int* in_sizes, int n_in,
                              void* d_out, int out_size, void* d_ws, size_t ws_size,
                              hipStream_t stream) {
    const float* q    = (const float*)d_in[0];
    const float* kv   = (const float*)d_in[1];
    const float* pos  = (const float*)d_in[2];
    const float* w    = (const float*)d_in[3];
    const float* bias = (const float*)d_in[4];
    const float* gam  = (const float*)d_in[5];
    const float* bet  = (const float*)d_in[6];
    float* out = (float*)d_out;

    const int n_blocks = 2 * IMG * IMG / TILE;   // 1024
    const size_t pkvb_bytes  = (size_t)2 * PDIM * PDIM * DIM * sizeof(unsigned short); // 2,803,712
    const size_t wfrag_bytes = (size_t)8 * 16 * 64 * 8 * sizeof(unsigned short);       // 131,072
    const size_t posA_bytes  = (size_t)NT_A * 64 * 8 * sizeof(unsigned short);         // 31,744

    if (ws_size >= pkvb_bytes + wfrag_bytes + posA_bytes) {
        unsigned short* pkvb  = (unsigned short*)d_ws;
        unsigned short* wfrag = (unsigned short*)((char*)d_ws + pkvb_bytes);
        unsigned short* posA  = (unsigned short*)((char*)d_ws + pkvb_bytes + wfrag_bytes);
        prep_kernel<<<NPAD + 128 + NT_A, 64, 0, stream>>>(kv, w, pos, pkvb, wfrag, posA);
        nca_kernel<<<n_blocks, 512, 0, stream>>>(q, pkvb, posA, wfrag, bias, gam, bet, out);
    } else {
        nca_kernel_nopad<<<n_blocks, 512, 0, stream>>>(q, kv, pos, w, bias, gam, bet, out);
    }
}

// Round 15
// 93.006 us; speedup vs baseline: 1.4979x; 1.1283x over previous
//
#include <hip/hip_runtime.h>
#include <math.h>

#define NB 11
#define PAD 5
#define DIM 128
#define NN 121        // NB*NB
#define S_TOT 484     // HEADS*NN
#define IMG 64
#define TILE 8        // pixels per block (x-contiguous)
#define PDIM 74       // IMG + 2*PAD
#define SCP 520       // sc_bf row stride (bf16), 16B-aligned, >= 512
#define PSCP 488      // psc row stride (f32)
#define UCOLS 18      // union columns: j_abs+5 for 8 pixels
#define UCELLS 198    // 11*18 union cells
#define NT_KV 50      // ceil(792/16) N-tiles in union kv GEMM
#define NT_POS 31     // N-tiles in pos GEMM (496 >= 484)
#define NPAD (2 * PDIM * PDIM)   // 10952 pad-copy blocks
#define LN_EPS 1e-5f

typedef __attribute__((ext_vector_type(8))) short bf16x8;
typedef __attribute__((ext_vector_type(4))) float f32x4;

static __device__ __forceinline__ unsigned short f2bf(float f) {
    unsigned u = __float_as_uint(f);
    u += 0x7FFF + ((u >> 16) & 1);          // round-to-nearest-even
    return (unsigned short)(u >> 16);
}

// Fused prologue (unchanged from R14): [0,NPAD) pad+bf16 kv;
// [NPAD,NPAD+128) W B-frag; [NPAD+128,+31) pos frag (s-major, reused as B).
__global__ __launch_bounds__(64) void prep_kernel(
    const float* __restrict__ kv, const float* __restrict__ w,
    const float* __restrict__ pos, unsigned short* __restrict__ pkvb,
    unsigned short* __restrict__ wfrag, unsigned short* __restrict__ posB)
{
    const int blk  = blockIdx.x;
    const int lane = threadIdx.x;
    if (blk < NPAD) {
        const int b  = blk / (PDIM * PDIM);
        const int rr = blk - b * PDIM * PDIM;
        const int py = rr / PDIM;
        const int px = rr - py * PDIM;
        const int ky = py - PAD, kx = px - PAD;
        unsigned v = 0;
        if ((unsigned)ky < (unsigned)IMG && (unsigned)kx < (unsigned)IMG) {
            const float2 f = *(const float2*)(kv + (((size_t)b * IMG + ky) * IMG + kx) * DIM + 2 * lane);
            v = (unsigned)f2bf(f.x) | ((unsigned)f2bf(f.y) << 16);
        }
        *(unsigned*)(pkvb + (size_t)blk * DIM + 2 * lane) = v;
    } else if (blk < NPAD + 128) {
        const int idx = blk - NPAD;
        const int t   = idx & 15;
        const int n   = ((idx >> 4) << 4) + (lane & 15);
        const int kb  = t * 32 + ((lane >> 4) << 3);
        unsigned short v[8];
        #pragma unroll
        for (int j = 0; j < 8; ++j) {
            const int k = kb + j;
            v[j] = (k < S_TOT) ? f2bf(w[(size_t)k * DIM + n]) : (unsigned short)0;
        }
        *(uint4*)(wfrag + (((size_t)idx * 64 + lane) << 3)) = *(const uint4*)v;
    } else {
        // posB[(nt*64+lane)*8+j] = pos4[s=16nt+(lane&15)][(lane>>4)*8+j],
        // pos4[s][d] = pos[s>>2][32*(s&3)+d]; zero rows p>120.
        const int nt   = blk - NPAD - 128;
        const int m    = lane & 15, quad = lane >> 4;
        const int p    = 4 * nt + (m >> 2);
        const int r    = m & 3;
        unsigned short v[8];
        #pragma unroll
        for (int j = 0; j < 8; ++j)
            v[j] = (p <= 120) ? f2bf(pos[(size_t)p * DIM + 32 * r + 8 * quad + j])
                              : (unsigned short)0;
        *(uint4*)(posB + (((size_t)nt * 64 + lane) << 3)) = *(const uint4*)v;
    }
}

// Single-arg launch bounds ONLY: (512,8)/(256,8) capped VGPR at 32 and spilled.
__global__ __launch_bounds__(512) void nca_kernel(
    const float* __restrict__ q, const unsigned short* __restrict__ pkvb,
    const unsigned short* __restrict__ posB, const unsigned short* __restrict__ wfrag,
    const float* __restrict__ bias, const float* __restrict__ gam,
    const float* __restrict__ bet, float* __restrict__ out)
{
    const int tile = blockIdx.x;         // 1024 tiles of 8 pixels along x
    const int pix0 = tile * TILE;
    const int x0 = pix0 & 63;
    const int y  = (pix0 >> 6) & 63;
    const int b  = pix0 >> 12;
    const int tid = threadIdx.x;

    __shared__ float qs[TILE][DIM];                          // 4 KB
    __shared__ float psc[TILE][PSCP];                        // 15.6 KB fp32 pos-scores
    __shared__ __align__(16) unsigned short sc_bf[TILE][SCP];// 8.3 KB bf16 scores
    __shared__ float mlp[TILE][DIM];                         // 4 KB

    // ---- stage q; zero sc pad [484,520) (phase B reads K up to 512) ----
    for (int i = tid; i < TILE * DIM; i += 512)
        qs[i >> 7][i & 127] = q[(size_t)pix0 * DIM + i];
    for (int i = tid; i < TILE * (SCP - S_TOT); i += 512)
        sc_bf[i / (SCP - S_TOT)][S_TOT + i % (SCP - S_TOT)] = 0;

    // ---- phase A: transposed score GEMMs. A = q rows: M = 16 = (px,h)
    // pairs: A[m][k] = q[4*mt+(m>>2)][32*(m&3)+k]. D row m=quad*4+reg ->
    // px = 4*mt+quad, h = reg.
    // Pass 1 (pos): B cols = s-slots (posB);  psc[px][s] = D[(px,h(s))][s].
    // Pass 2 (kv):  B cols = union cells (11 x 18) x 4 r-slices, shared by
    // all 8 pixels; score[px][s] = D[(px,h)][slot] + psc, s = 44i+4(u-px)+r.
    {
        const int wid  = tid >> 6;
        const int lane = tid & 63;
        const int n    = lane & 15, quad = lane >> 4;
        const int mt   = wid & 1;          // pixel half
        const int w4   = wid >> 1;         // tile-stride offset 0..3
        const int pxl  = 4 * mt + quad;    // this lane's pixel

        // A-frag (one-time): row m = n, k = 8*quad+j
        const float* qa = q + ((size_t)(pix0 + 4 * mt + (n >> 2))) * DIM
                            + 32 * (n & 3) + 8 * quad;
        const float4 fa0 = *(const float4*)qa;
        const float4 fa1 = *(const float4*)(qa + 4);
        unsigned short aq_[8] = {f2bf(fa0.x), f2bf(fa0.y), f2bf(fa0.z), f2bf(fa0.w),
                                 f2bf(fa1.x), f2bf(fa1.y), f2bf(fa1.z), f2bf(fa1.w)};
        const bf16x8 Aq = *(const bf16x8*)aq_;

        // ---- pass 1: pos GEMM -> psc (fp32) ----
        {
            const unsigned short* pb = posB + ((size_t)lane << 3);
            int nt = w4;
            bf16x8 Bc = *(const bf16x8*)(pb + (size_t)nt * 512);
            while (nt < NT_POS) {
                const int ntn = nt + 4;
                bf16x8 Bn = Bc;
                if (ntn < NT_POS) Bn = *(const bf16x8*)(pb + (size_t)ntn * 512);
                f32x4 acc = {0.f, 0.f, 0.f, 0.f};
                acc = __builtin_amdgcn_mfma_f32_16x16x32_bf16(Aq, Bc, acc, 0, 0, 0);
                const int s = 16 * nt + n;
                if (s < S_TOT) {
                    const int h = (271 * s) >> 15;   // s/121, exact for s<512
                    const float v = (h == 0) ? acc[0] : (h == 1) ? acc[1]
                                  : (h == 2) ? acc[2] : acc[3];
                    psc[pxl][s] = v;
                }
                Bc = Bn; nt = ntn;
            }
        }
        __syncthreads();

        // ---- pass 2: union kv GEMM -> sc_bf (adds psc, one bf16 round) ----
        {
            const int r  = n & 3;
            const int co = 32 * r + 8 * quad;
            const unsigned short* kvb = pkvb
                + ((size_t)((b * PDIM + y) * PDIM) + x0) * DIM + co;
            int c = 4 * w4 + (n >> 2);     // union cell (<=15 -> i=0,u=c)
            int i = 0, u = c;
            int nt = w4;
            bf16x8 Bc = *(const bf16x8*)(kvb + (size_t)(i * PDIM + u) * DIM);
            while (nt < NT_KV) {
                // advance per-lane cell by 16 (nt += 4), clamp pad cells
                int cn = c + 16, in_ = i, un = u + 16;
                if (un >= UCOLS) { un -= UCOLS; ++in_; }
                if (cn > UCELLS - 1) { in_ = 10; un = UCOLS - 1; }
                bf16x8 Bn = Bc;
                if (nt + 4 < NT_KV)
                    Bn = *(const bf16x8*)(kvb + (size_t)(in_ * PDIM + un) * DIM);
                f32x4 acc = {0.f, 0.f, 0.f, 0.f};
                acc = __builtin_amdgcn_mfma_f32_16x16x32_bf16(Aq, Bc, acc, 0, 0, 0);
                const int jr = u - pxl;               // j_rel
                if ((unsigned)jr < 11u) {
                    const int s = 44 * i + 4 * jr + r;
                    const int h = (271 * s) >> 15;
                    const float v = ((h == 0) ? acc[0] : (h == 1) ? acc[1]
                                   : (h == 2) ? acc[2] : acc[3]) + psc[pxl][s];
                    sc_bf[pxl][s] = f2bf(v);
                }
                Bc = Bn; c = cn; i = in_; u = un; nt += 4;
            }
        }
    }
    __syncthreads();

    // ---- phase B: MFMA MLP: wave = n-tile of 16 channels, K=512 ----
    {
        const int wv   = tid >> 6;
        const int lane = tid & 63;
        const int m    = lane & 15;
        const int quad = lane >> 4;
        const unsigned short* bfr = wfrag + (((size_t)(wv * 16) * 64 + lane) << 3);
        const unsigned short* ap  = &sc_bf[m & 7][quad * 8];
        f32x4 acc = {0.f, 0.f, 0.f, 0.f};
        bf16x8 b0 = *(const bf16x8*)(bfr);
        bf16x8 b1 = *(const bf16x8*)(bfr + 512);
        bf16x8 b2 = *(const bf16x8*)(bfr + 1024);
        bf16x8 b3 = *(const bf16x8*)(bfr + 1536);
        #pragma unroll
        for (int t = 0; t < 16; ++t) {
            const bf16x8 a = *(const bf16x8*)(ap + t * 32);
            bf16x8 bn = b3;
            if (t + 4 < 16) bn = *(const bf16x8*)(bfr + (t + 4) * 512);
            acc = __builtin_amdgcn_mfma_f32_16x16x32_bf16(a, b0, acc, 0, 0, 0);
            b0 = b1; b1 = b2; b2 = b3; b3 = bn;
        }
        if (quad < 2) {
            #pragma unroll
            for (int reg = 0; reg < 4; ++reg)
                mlp[quad * 4 + reg][wv * 16 + m] = acc[reg];
        }
    }
    __syncthreads();

    // ---- epilogue: bias, exact GELU, residual ----
    for (int idx = tid; idx < TILE * DIM; idx += 512) {
        const int pix = idx >> 7, cc = idx & 127;
        const float v = mlp[pix][cc] + bias[cc];
        const float gl = 0.5f * v * (1.f + erff(v * 0.70710678118654752f));
        qs[pix][cc] += gl;               // x = q + gelu(mlp)
    }
    __syncthreads();

    // ---- LayerNorm: wave wid owns pixel wid ----
    {
        const int lane = tid & 63, wid = tid >> 6;
        const float v0 = qs[wid][lane], v1 = qs[wid][lane + 64];
        float sum = v0 + v1;
        #pragma unroll
        for (int off = 1; off < 64; off <<= 1) sum += __shfl_xor(sum, off, 64);
        const float mean = sum * (1.f / 128.f);
        const float d0 = v0 - mean, d1 = v1 - mean;
        float sq = d0 * d0 + d1 * d1;
        #pragma unroll
        for (int off = 1; off < 64; off <<= 1) sq += __shfl_xor(sq, off, 64);
        const float rstd = rsqrtf(sq * (1.f / 128.f) + LN_EPS);
        float* op = out + (size_t)(pix0 + wid) * DIM;
        op[lane]      = d0 * rstd * gam[lane]      + bet[lane];
        op[lane + 64] = d1 * rstd * gam[lane + 64] + bet[lane + 64];
    }
}

// Fallback (fp32, bounds-checked, no workspace).
__global__ __launch_bounds__(512) void nca_kernel_nopad(
    const float* __restrict__ q, const float* __restrict__ kvsrc,
    const float* __restrict__ pos, const float* __restrict__ w,
    const float* __restrict__ bias, const float* __restrict__ gam,
    const float* __restrict__ bet, float* __restrict__ out)
{
    const int tile = blockIdx.x;
    const int pix0 = tile * TILE;
    const int x0 = pix0 & 63;
    const int y  = (pix0 >> 6) & 63;
    const int b  = pix0 >> 12;
    const int tid = threadIdx.x;

    __shared__ float qs[TILE][DIM];
    __shared__ float sc[S_TOT][TILE];
    __shared__ float part[4][TILE][DIM];

    for (int i = tid; i < TILE * DIM; i += 512)
        qs[i >> 7][i & 127] = q[(size_t)pix0 * DIM + i];
    __syncthreads();

    {
        const int pix = tid >> 6;
        const int grp = (tid >> 4) & 3;
        const int l16 = tid & 15;
        const int r   = l16 >> 2;
        const int dq  = 8 * (l16 & 3);
        const int ch  = 8 * l16;
        const int xpix = x0 + pix;
        int p = grp, i = 0, j = grp;
        int h = 0, rem = 4 * grp + r;
        const float* kvb  = kvsrc + (size_t)b * IMG * IMG * DIM + ch;
        const float* posb = pos + ch;
        float4 q0 = *(const float4*)(&qs[pix][dq]);
        float4 q1 = *(const float4*)(&qs[pix][dq + 4]);
        for (int it = 0; it < 31; ++it) {
            if (p <= 120) {
                float4 k0 = make_float4(0.f,0.f,0.f,0.f), k1 = k0;
                const int ky = y + i - PAD, kx = xpix + j - PAD;
                if (((unsigned)ky < (unsigned)IMG) && ((unsigned)kx < (unsigned)IMG)) {
                    const float* kp = kvb + (size_t)(ky * IMG + kx) * DIM;
                    k0 = *(const float4*)(kp);
                    k1 = *(const float4*)(kp + 4);
                }
                const float4 p0 = *(const float4*)(posb + (size_t)p * DIM);
                const float4 p1 = *(const float4*)(posb + (size_t)p * DIM + 4);
                float t = (k0.x + p0.x) * q0.x + (k0.y + p0.y) * q0.y
                        + (k0.z + p0.z) * q0.z + (k0.w + p0.w) * q0.w
                        + (k1.x + p1.x) * q1.x + (k1.y + p1.y) * q1.y
                        + (k1.z + p1.z) * q1.z + (k1.w + p1.w) * q1.w;
                t += __shfl_xor(t, 1, 64);
                t += __shfl_xor(t, 2, 64);
                if ((l16 & 3) == 0) sc[4 * p + r][pix] = t;
            }
            p += 4; j += 4;
            if (j >= NB) { j -= NB; ++i; }
            rem += 16;
            if (rem >= NN) {
                rem -= NN; ++h;
                q0 = *(const float4*)(&qs[pix][h * 32 + dq]);
                q1 = *(const float4*)(&qs[pix][h * 32 + dq + 4]);
            }
        }
    }
    __syncthreads();

    {
        const int l  = tid & 63;
        const int wv = tid >> 6;
        const int g  = wv >> 1;
        const int ph = wv & 1;
        const float* wc  = w + (size_t)(g * NN) * DIM + l;
        const float* scp = &sc[g * NN][ph * 4];
        float a00=0,a01=0,a10=0,a11=0,a20=0,a21=0,a30=0,a31=0;
        #pragma unroll 2
        for (int s = 0; s < NN; ++s) {
            const float4 sv = *(const float4*)(scp + s * 8);
            const float w0 = wc[(size_t)s * DIM];
            const float w1 = wc[(size_t)s * DIM + 64];
            a00 += sv.x * w0; a01 += sv.x * w1;
            a10 += sv.y * w0; a11 += sv.y * w1;
            a20 += sv.z * w0; a21 += sv.z * w1;
            a30 += sv.w * w0; a31 += sv.w * w1;
        }
        const int pb = ph * 4;
        part[g][pb+0][l] = a00; part[g][pb+0][l+64] = a01;
        part[g][pb+1][l] = a10; part[g][pb+1][l+64] = a11;
        part[g][pb+2][l] = a20; part[g][pb+2][l+64] = a21;
        part[g][pb+3][l] = a30; part[g][pb+3][l+64] = a31;
    }
    __syncthreads();

    for (int idx = tid; idx < TILE * DIM; idx += 512) {
        const int pix = idx >> 7, cc = idx & 127;
        float v = part[0][pix][cc] + part[1][pix][cc]
                + part[2][pix][cc] + part[3][pix][cc] + bias[cc];
        const float gl = 0.5f * v * (1.f + erff(v * 0.70710678118654752f));
        qs[pix][cc] += gl;
    }
    __syncthreads();

    {
        const int lane = tid & 63, wid = tid >> 6;
        const float v0 = qs[wid][lane], v1 = qs[wid][lane + 64];
        float sum = v0 + v1;
        #pragma unroll
        for (int off = 1; off < 64; off <<= 1) sum += __shfl_xor(sum, off, 64);
        const float mean = sum * (1.f / 128.f);
        const float d0 = v0 - mean, d1 = v1 - mean;
        float sq = d0 * d0 + d1 * d1;
        #pragma unroll
        for (int off = 1; off < 64; off <<= 1) sq += __shfl_xor(sq, off, 64);
        const float rstd = rsqrtf(sq * (1.f / 128.f) + LN_EPS);
        float* op = out + (size_t)(pix0 + wid) * DIM;
        op[lane]      = d0 * rstd * gam[lane]      + bet[lane];
        op[lane + 64] = d1 * rstd * gam[lane + 64] + bet[lane + 64];
    }
}

extern "C" void kernel_launch(void* const* d_in, const int* in_sizes, int n_in,
                              void* d_out, int out_size, void* d_ws, size_t ws_size,
                              hipStream_t stream) {
    const float* q    = (const float*)d_in[0];
    const float* kv   = (const float*)d_in[1];
    const float* pos  = (const float*)d_in[2];
    const float* w    = (const float*)d_in[3];
    const float* bias = (const float*)d_in[4];
    const float* gam  = (const float*)d_in[5];
    const float* bet  = (const float*)d_in[6];
    float* out = (float*)d_out;

    const int n_blocks = 2 * IMG * IMG / TILE;   // 1024
    const size_t pkvb_bytes  = (size_t)2 * PDIM * PDIM * DIM * sizeof(unsigned short); // 2,803,712
    const size_t wfrag_bytes = (size_t)8 * 16 * 64 * 8 * sizeof(unsigned short);       // 131,072
    const size_t posB_bytes  = (size_t)NT_POS * 64 * 8 * sizeof(unsigned short);       // 31,744

    if (ws_size >= pkvb_bytes + wfrag_bytes + posB_bytes) {
        unsigned short* pkvb  = (unsigned short*)d_ws;
        unsigned short* wfrag = (unsigned short*)((char*)d_ws + pkvb_bytes);
        unsigned short* posB  = (unsigned short*)((char*)d_ws + pkvb_bytes + wfrag_bytes);
        prep_kernel<<<NPAD + 128 + NT_POS, 64, 0, stream>>>(kv, w, pos, pkvb, wfrag, posB);
        nca_kernel<<<n_blocks, 512, 0, stream>>>(q, pkvb, posB, wfrag, bias, gam, bet, out);
    } else {
        nca_kernel_nopad<<<n_blocks, 512, 0, stream>>>(q, kv, pos, w, bias, gam, bet, out);
    }
}

// Round 16
// 91.123 us; speedup vs baseline: 1.5289x; 1.0207x over previous
//
#include <hip/hip_runtime.h>
#include <math.h>

#define NB 11
#define PAD 5
#define DIM 128
#define NN 121        // NB*NB
#define S_TOT 484     // HEADS*NN
#define IMG 64
#define TILE 8        // pixels per block (x-contiguous)
#define PDIM 74       // IMG + 2*PAD
#define SCP 520       // sc_bf row stride (bf16), 16B-aligned, >= 512
#define PSCP 488      // psc row stride (f32)
#define UCOLS 18      // union columns: j_abs+5 for 8 pixels
#define UCELLS 198    // 11*18 union cells
#define NT_KV 50      // ceil(792/16) N-tiles in union kv GEMM
#define NT_POS 31     // N-tiles in pos GEMM (496 >= 484)
#define NPAD (2 * PDIM * PDIM)   // 10952 padded kv rows
#define KVB ((NPAD + 3) / 4)     // 2738 kv prep blocks (4 rows each)
#define LN_EPS 1e-5f

typedef __attribute__((ext_vector_type(8))) short bf16x8;
typedef __attribute__((ext_vector_type(4))) float f32x4;

static __device__ __forceinline__ unsigned short f2bf(float f) {
    unsigned u = __float_as_uint(f);
    u += 0x7FFF + ((u >> 16) & 1);          // round-to-nearest-even
    return (unsigned short)(u >> 16);
}

// Fused prologue, 256-thread blocks (4 work-units each):
// blocks [0,KVB): pad+bf16 kv rows; [KVB,KVB+32): W B-frag; [KVB+32,+8): posB.
__global__ __launch_bounds__(256) void prep_kernel(
    const float* __restrict__ kv, const float* __restrict__ w,
    const float* __restrict__ pos, unsigned short* __restrict__ pkvb,
    unsigned short* __restrict__ wfrag, unsigned short* __restrict__ posB)
{
    const int blk  = blockIdx.x;
    const int lane = threadIdx.x & 63;
    const int sub  = threadIdx.x >> 6;     // unit within block, 0..3
    if (blk < KVB) {
        const int row = blk * 4 + sub;     // padded row index
        if (row < NPAD) {
            const int b  = row / (PDIM * PDIM);
            const int rr = row - b * PDIM * PDIM;
            const int py = rr / PDIM;
            const int px = rr - py * PDIM;
            const int ky = py - PAD, kx = px - PAD;
            unsigned v = 0;
            if ((unsigned)ky < (unsigned)IMG && (unsigned)kx < (unsigned)IMG) {
                const float2 f = *(const float2*)(kv + (((size_t)b * IMG + ky) * IMG + kx) * DIM + 2 * lane);
                v = (unsigned)f2bf(f.x) | ((unsigned)f2bf(f.y) << 16);
            }
            *(unsigned*)(pkvb + (size_t)row * DIM + 2 * lane) = v;
        }
    } else if (blk < KVB + 32) {
        const int idx = (blk - KVB) * 4 + sub;   // 0..127
        const int t   = idx & 15;
        const int n   = ((idx >> 4) << 4) + (lane & 15);
        const int kb  = t * 32 + ((lane >> 4) << 3);
        unsigned short v[8];
        #pragma unroll
        for (int j = 0; j < 8; ++j) {
            const int k = kb + j;
            v[j] = (k < S_TOT) ? f2bf(w[(size_t)k * DIM + n]) : (unsigned short)0;
        }
        *(uint4*)(wfrag + (((size_t)idx * 64 + lane) << 3)) = *(const uint4*)v;
    } else {
        // posB[(nt*64+lane)*8+j] = pos4[s=16nt+(lane&15)][(lane>>4)*8+j],
        // pos4[s][d] = pos[s>>2][32*(s&3)+d]; zero rows p>120.
        const int nt = (blk - KVB - 32) * 4 + sub;
        if (nt < NT_POS) {
            const int m    = lane & 15, quad = lane >> 4;
            const int p    = 4 * nt + (m >> 2);
            const int r    = m & 3;
            unsigned short v[8];
            #pragma unroll
            for (int j = 0; j < 8; ++j)
                v[j] = (p <= 120) ? f2bf(pos[(size_t)p * DIM + 32 * r + 8 * quad + j])
                                  : (unsigned short)0;
            *(uint4*)(posB + (((size_t)nt * 64 + lane) << 3)) = *(const uint4*)v;
        }
    }
}

// Single-arg launch bounds ONLY: (512,8)/(256,8) capped VGPR at 32 and spilled.
__global__ __launch_bounds__(512) void nca_kernel(
    const float* __restrict__ q, const unsigned short* __restrict__ pkvb,
    const unsigned short* __restrict__ posB, const unsigned short* __restrict__ wfrag,
    const float* __restrict__ bias, const float* __restrict__ gam,
    const float* __restrict__ bet, float* __restrict__ out)
{
    const int tile = blockIdx.x;         // 1024 tiles of 8 pixels along x
    const int pix0 = tile * TILE;
    const int x0 = pix0 & 63;
    const int y  = (pix0 >> 6) & 63;
    const int b  = pix0 >> 12;
    const int tid = threadIdx.x;

    __shared__ float qs[TILE][DIM];                          // 4 KB
    __shared__ float psc[TILE][PSCP];                        // 15.6 KB fp32 pos-scores
    __shared__ __align__(16) unsigned short sc_bf[TILE][SCP];// 8.3 KB bf16 scores
    __shared__ float mlp[TILE][DIM];                         // 4 KB

    // ---- stage q; zero sc pad [484,520) (phase B reads K up to 512) ----
    for (int i = tid; i < TILE * DIM; i += 512)
        qs[i >> 7][i & 127] = q[(size_t)pix0 * DIM + i];
    for (int i = tid; i < TILE * (SCP - S_TOT); i += 512)
        sc_bf[i / (SCP - S_TOT)][S_TOT + i % (SCP - S_TOT)] = 0;

    // ---- phase A: transposed score GEMMs. A = q rows: M = 16 = (px,h)
    // pairs: A[m][k] = q[4*mt+(m>>2)][32*(m&3)+k]. D row m=quad*4+reg ->
    // px = 4*mt+quad, h = reg.
    // Pass 1 (pos): B cols = s-slots (posB);  psc[px][s] = D[(px,h(s))][s].
    // Pass 2 (kv):  B cols = union cells (11 x 18) x 4 r-slices, shared by
    // all 8 pixels; score[px][s] = D[(px,h)][slot] + psc, s = 44i+4(u-px)+r.
    {
        const int wid  = tid >> 6;
        const int lane = tid & 63;
        const int n    = lane & 15, quad = lane >> 4;
        const int mt   = wid & 1;          // pixel half
        const int w4   = wid >> 1;         // tile-stride offset 0..3
        const int pxl  = 4 * mt + quad;    // this lane's pixel

        // A-frag (one-time): row m = n, k = 8*quad+j
        const float* qa = q + ((size_t)(pix0 + 4 * mt + (n >> 2))) * DIM
                            + 32 * (n & 3) + 8 * quad;
        const float4 fa0 = *(const float4*)qa;
        const float4 fa1 = *(const float4*)(qa + 4);
        unsigned short aq_[8] = {f2bf(fa0.x), f2bf(fa0.y), f2bf(fa0.z), f2bf(fa0.w),
                                 f2bf(fa1.x), f2bf(fa1.y), f2bf(fa1.z), f2bf(fa1.w)};
        const bf16x8 Aq = *(const bf16x8*)aq_;

        // ---- pass 1: pos GEMM -> psc (fp32) ----
        {
            const unsigned short* pb = posB + ((size_t)lane << 3);
            int nt = w4;
            bf16x8 Bc = *(const bf16x8*)(pb + (size_t)nt * 512);
            while (nt < NT_POS) {
                const int ntn = nt + 4;
                bf16x8 Bn = Bc;
                if (ntn < NT_POS) Bn = *(const bf16x8*)(pb + (size_t)ntn * 512);
                f32x4 acc = {0.f, 0.f, 0.f, 0.f};
                acc = __builtin_amdgcn_mfma_f32_16x16x32_bf16(Aq, Bc, acc, 0, 0, 0);
                const int s = 16 * nt + n;
                if (s < S_TOT) {
                    const int h = (271 * s) >> 15;   // s/121, exact for s<512
                    const float v = (h == 0) ? acc[0] : (h == 1) ? acc[1]
                                  : (h == 2) ? acc[2] : acc[3];
                    psc[pxl][s] = v;
                }
                Bc = Bn; nt = ntn;
            }
        }
        __syncthreads();

        // ---- pass 2: union kv GEMM -> sc_bf (adds psc, one bf16 round) ----
        {
            const int r  = n & 3;
            const int co = 32 * r + 8 * quad;
            const unsigned short* kvb = pkvb
                + ((size_t)((b * PDIM + y) * PDIM) + x0) * DIM + co;
            int c = 4 * w4 + (n >> 2);     // union cell (<=15 -> i=0,u=c)
            int i = 0, u = c;
            int nt = w4;
            bf16x8 Bc = *(const bf16x8*)(kvb + (size_t)(i * PDIM + u) * DIM);
            while (nt < NT_KV) {
                // advance per-lane cell by 16 (nt += 4), clamp pad cells
                int cn = c + 16, in_ = i, un = u + 16;
                if (un >= UCOLS) { un -= UCOLS; ++in_; }
                if (cn > UCELLS - 1) { in_ = 10; un = UCOLS - 1; }
                bf16x8 Bn = Bc;
                if (nt + 4 < NT_KV)
                    Bn = *(const bf16x8*)(kvb + (size_t)(in_ * PDIM + un) * DIM);
                f32x4 acc = {0.f, 0.f, 0.f, 0.f};
                acc = __builtin_amdgcn_mfma_f32_16x16x32_bf16(Aq, Bc, acc, 0, 0, 0);
                const int jr = u - pxl;               // j_rel
                if ((unsigned)jr < 11u) {
                    const int s = 44 * i + 4 * jr + r;
                    const int h = (271 * s) >> 15;
                    const float v = ((h == 0) ? acc[0] : (h == 1) ? acc[1]
                                   : (h == 2) ? acc[2] : acc[3]) + psc[pxl][s];
                    sc_bf[pxl][s] = f2bf(v);
                }
                Bc = Bn; c = cn; i = in_; u = un; nt += 4;
            }
        }
    }
    __syncthreads();

    // ---- phase B: MFMA MLP: wave = n-tile of 16 channels, K=512 ----
    {
        const int wv   = tid >> 6;
        const int lane = tid & 63;
        const int m    = lane & 15;
        const int quad = lane >> 4;
        const unsigned short* bfr = wfrag + (((size_t)(wv * 16) * 64 + lane) << 3);
        const unsigned short* ap  = &sc_bf[m & 7][quad * 8];
        f32x4 acc = {0.f, 0.f, 0.f, 0.f};
        bf16x8 b0 = *(const bf16x8*)(bfr);
        bf16x8 b1 = *(const bf16x8*)(bfr + 512);
        bf16x8 b2 = *(const bf16x8*)(bfr + 1024);
        bf16x8 b3 = *(const bf16x8*)(bfr + 1536);
        #pragma unroll
        for (int t = 0; t < 16; ++t) {
            const bf16x8 a = *(const bf16x8*)(ap + t * 32);
            bf16x8 bn = b3;
            if (t + 4 < 16) bn = *(const bf16x8*)(bfr + (t + 4) * 512);
            acc = __builtin_amdgcn_mfma_f32_16x16x32_bf16(a, b0, acc, 0, 0, 0);
            b0 = b1; b1 = b2; b2 = b3; b3 = bn;
        }
        if (quad < 2) {
            #pragma unroll
            for (int reg = 0; reg < 4; ++reg)
                mlp[quad * 4 + reg][wv * 16 + m] = acc[reg];
        }
    }
    __syncthreads();

    // ---- epilogue: bias, exact GELU, residual ----
    for (int idx = tid; idx < TILE * DIM; idx += 512) {
        const int pix = idx >> 7, cc = idx & 127;
        const float v = mlp[pix][cc] + bias[cc];
        const float gl = 0.5f * v * (1.f + erff(v * 0.70710678118654752f));
        qs[pix][cc] += gl;               // x = q + gelu(mlp)
    }
    __syncthreads();

    // ---- LayerNorm: wave wid owns pixel wid ----
    {
        const int lane = tid & 63, wid = tid >> 6;
        const float v0 = qs[wid][lane], v1 = qs[wid][lane + 64];
        float sum = v0 + v1;
        #pragma unroll
        for (int off = 1; off < 64; off <<= 1) sum += __shfl_xor(sum, off, 64);
        const float mean = sum * (1.f / 128.f);
        const float d0 = v0 - mean, d1 = v1 - mean;
        float sq = d0 * d0 + d1 * d1;
        #pragma unroll
        for (int off = 1; off < 64; off <<= 1) sq += __shfl_xor(sq, off, 64);
        const float rstd = rsqrtf(sq * (1.f / 128.f) + LN_EPS);
        float* op = out + (size_t)(pix0 + wid) * DIM;
        op[lane]      = d0 * rstd * gam[lane]      + bet[lane];
        op[lane + 64] = d1 * rstd * gam[lane + 64] + bet[lane + 64];
    }
}

// Fallback (fp32, bounds-checked, no workspace).
__global__ __launch_bounds__(512) void nca_kernel_nopad(
    const float* __restrict__ q, const float* __restrict__ kvsrc,
    const float* __restrict__ pos, const float* __restrict__ w,
    const float* __restrict__ bias, const float* __restrict__ gam,
    const float* __restrict__ bet, float* __restrict__ out)
{
    const int tile = blockIdx.x;
    const int pix0 = tile * TILE;
    const int x0 = pix0 & 63;
    const int y  = (pix0 >> 6) & 63;
    const int b  = pix0 >> 12;
    const int tid = threadIdx.x;

    __shared__ float qs[TILE][DIM];
    __shared__ float sc[S_TOT][TILE];
    __shared__ float part[4][TILE][DIM];

    for (int i = tid; i < TILE * DIM; i += 512)
        qs[i >> 7][i & 127] = q[(size_t)pix0 * DIM + i];
    __syncthreads();

    {
        const int pix = tid >> 6;
        const int grp = (tid >> 4) & 3;
        const int l16 = tid & 15;
        const int r   = l16 >> 2;
        const int dq  = 8 * (l16 & 3);
        const int ch  = 8 * l16;
        const int xpix = x0 + pix;
        int p = grp, i = 0, j = grp;
        int h = 0, rem = 4 * grp + r;
        const float* kvb  = kvsrc + (size_t)b * IMG * IMG * DIM + ch;
        const float* posb = pos + ch;
        float4 q0 = *(const float4*)(&qs[pix][dq]);
        float4 q1 = *(const float4*)(&qs[pix][dq + 4]);
        for (int it = 0; it < 31; ++it) {
            if (p <= 120) {
                float4 k0 = make_float4(0.f,0.f,0.f,0.f), k1 = k0;
                const int ky = y + i - PAD, kx = xpix + j - PAD;
                if (((unsigned)ky < (unsigned)IMG) && ((unsigned)kx < (unsigned)IMG)) {
                    const float* kp = kvb + (size_t)(ky * IMG + kx) * DIM;
                    k0 = *(const float4*)(kp);
                    k1 = *(const float4*)(kp + 4);
                }
                const float4 p0 = *(const float4*)(posb + (size_t)p * DIM);
                const float4 p1 = *(const float4*)(posb + (size_t)p * DIM + 4);
                float t = (k0.x + p0.x) * q0.x + (k0.y + p0.y) * q0.y
                        + (k0.z + p0.z) * q0.z + (k0.w + p0.w) * q0.w
                        + (k1.x + p1.x) * q1.x + (k1.y + p1.y) * q1.y
                        + (k1.z + p1.z) * q1.z + (k1.w + p1.w) * q1.w;
                t += __shfl_xor(t, 1, 64);
                t += __shfl_xor(t, 2, 64);
                if ((l16 & 3) == 0) sc[4 * p + r][pix] = t;
            }
            p += 4; j += 4;
            if (j >= NB) { j -= NB; ++i; }
            rem += 16;
            if (rem >= NN) {
                rem -= NN; ++h;
                q0 = *(const float4*)(&qs[pix][h * 32 + dq]);
                q1 = *(const float4*)(&qs[pix][h * 32 + dq + 4]);
            }
        }
    }
    __syncthreads();

    {
        const int l  = tid & 63;
        const int wv = tid >> 6;
        const int g  = wv >> 1;
        const int ph = wv & 1;
        const float* wc  = w + (size_t)(g * NN) * DIM + l;
        const float* scp = &sc[g * NN][ph * 4];
        float a00=0,a01=0,a10=0,a11=0,a20=0,a21=0,a30=0,a31=0;
        #pragma unroll 2
        for (int s = 0; s < NN; ++s) {
            const float4 sv = *(const float4*)(scp + s * 8);
            const float w0 = wc[(size_t)s * DIM];
            const float w1 = wc[(size_t)s * DIM + 64];
            a00 += sv.x * w0; a01 += sv.x * w1;
            a10 += sv.y * w0; a11 += sv.y * w1;
            a20 += sv.z * w0; a21 += sv.z * w1;
            a30 += sv.w * w0; a31 += sv.w * w1;
        }
        const int pb = ph * 4;
        part[g][pb+0][l] = a00; part[g][pb+0][l+64] = a01;
        part[g][pb+1][l] = a10; part[g][pb+1][l+64] = a11;
        part[g][pb+2][l] = a20; part[g][pb+2][l+64] = a21;
        part[g][pb+3][l] = a30; part[g][pb+3][l+64] = a31;
    }
    __syncthreads();

    for (int idx = tid; idx < TILE * DIM; idx += 512) {
        const int pix = idx >> 7, cc = idx & 127;
        float v = part[0][pix][cc] + part[1][pix][cc]
                + part[2][pix][cc] + part[3][pix][cc] + bias[cc];
        const float gl = 0.5f * v * (1.f + erff(v * 0.70710678118654752f));
        qs[pix][cc] += gl;
    }
    __syncthreads();

    {
        const int lane = tid & 63, wid = tid >> 6;
        const float v0 = qs[wid][lane], v1 = qs[wid][lane + 64];
        float sum = v0 + v1;
        #pragma unroll
        for (int off = 1; off < 64; off <<= 1) sum += __shfl_xor(sum, off, 64);
        const float mean = sum * (1.f / 128.f);
        const float d0 = v0 - mean, d1 = v1 - mean;
        float sq = d0 * d0 + d1 * d1;
        #pragma unroll
        for (int off = 1; off < 64; off <<= 1) sq += __shfl_xor(sq, off, 64);
        const float rstd = rsqrtf(sq * (1.f / 128.f) + LN_EPS);
        float* op = out + (size_t)(pix0 + wid) * DIM;
        op[lane]      = d0 * rstd * gam[lane]      + bet[lane];
        op[lane + 64] = d1 * rstd * gam[lane + 64] + bet[lane + 64];
    }
}

extern "C" void kernel_launch(void* const* d_in, const int* in_sizes, int n_in,
                              void* d_out, int out_size, void* d_ws, size_t ws_size,
                              hipStream_t stream) {
    const float* q    = (const float*)d_in[0];
    const float* kv   = (const float*)d_in[1];
    const float* pos  = (const float*)d_in[2];
    const float* w    = (const float*)d_in[3];
    const float* bias = (const float*)d_in[4];
    const float* gam  = (const float*)d_in[5];
    const float* bet  = (const float*)d_in[6];
    float* out = (float*)d_out;

    const int n_blocks = 2 * IMG * IMG / TILE;   // 1024
    const size_t pkvb_bytes  = (size_t)2 * PDIM * PDIM * DIM * sizeof(unsigned short); // 2,803,712
    const size_t wfrag_bytes = (size_t)8 * 16 * 64 * 8 * sizeof(unsigned short);       // 131,072
    const size_t posB_bytes  = (size_t)NT_POS * 64 * 8 * sizeof(unsigned short);       // 31,744

    if (ws_size >= pkvb_bytes + wfrag_bytes + posB_bytes) {
        unsigned short* pkvb  = (unsigned short*)d_ws;
        unsigned short* wfrag = (unsigned short*)((char*)d_ws + pkvb_bytes);
        unsigned short* posB  = (unsigned short*)((char*)d_ws + pkvb_bytes + wfrag_bytes);
        const int prep_blocks = KVB + 32 + (NT_POS + 3) / 4;   // 2738+32+8
        prep_kernel<<<prep_blocks, 256, 0, stream>>>(kv, w, pos, pkvb, wfrag, posB);
        nca_kernel<<<n_blocks, 512, 0, stream>>>(q, pkvb, posB, wfrag, bias, gam, bet, out);
    } else {
        nca_kernel_nopad<<<n_blocks, 512, 0, stream>>>(q, kv, pos, w, bias, gam, bet, out);
    }
}